// Round 3
// baseline (6037.473 us; speedup 1.0000x reference)
//
#include <hip/hip_runtime.h>
#include <math.h>

#define NCC 64
#define NB 8
#define VOL (NCC*NCC*NCC)      // 262144 = 2^18
#define TOT (NB*VOL)           // 2097152
#define WTOT 170869            // total weight elements

typedef unsigned short u16;
__device__ __forceinline__ float b2f(u16 h){ return __uint_as_float(((unsigned)h)<<16); }
__device__ __forceinline__ u16 f2b(float f){
  unsigned u = __float_as_uint(f);
  unsigned r = (u + 0x7FFFu + ((u>>16)&1u)) >> 16;
  return (u16)r;
}

// ---------------- dtype sniff: 1 = bf16, 0 = f32 ----------------
__global__ __launch_bounds__(256) void k_sniff(const u16* __restrict__ x, int* __restrict__ flag) {
  __shared__ int cnt;
  if (threadIdx.x == 0) cnt = 0;
  __syncthreads();
  int sane = 0;
  for (int i = threadIdx.x; i < 1024; i += 256) {
    u16 h = x[2 * i];                 // even u16: bf16 value OR f32 low-mantissa garbage
    int e = (h >> 7) & 0xFF;
    if (h == 0 || (e >= 0x68 && e <= 0x8F)) sane++;
  }
  atomicAdd(&cnt, sane);
  __syncthreads();
  if (threadIdx.x == 0) flag[0] = (cnt >= 768) ? 1 : 0;
}

// ---------------- generic slice convert (dtype-flagged) ----------------
__global__ __launch_bounds__(256) void k_cvt(const void* __restrict__ in, size_t eoff,
                                             float* __restrict__ out, const int* __restrict__ flag) {
  size_t i = (size_t)blockIdx.x * 256 + threadIdx.x;
  if (*flag) out[i] = b2f(((const u16*)in)[eoff + i]);
  else       out[i] = ((const float*)in)[eoff + i];
}

// ---------------- all-weights convert ----------------
__global__ __launch_bounds__(256) void k_cvtall(
    const void* s0, const void* s1, const void* s2, const void* s3,
    const void* s4, const void* s5, const void* s6, const void* s7,
    const void* s8, const void* s9, const void* s10, const void* s11,
    const void* s12, const void* s13, const void* s14, const void* s15,
    float* __restrict__ out, const int* __restrict__ flag) {
  const void* ps[16] = {s0,s1,s2,s3,s4,s5,s6,s7,s8,s9,s10,s11,s12,s13,s14,s15};
  const int offs[17] = {0,432,440,7352,14264,14296,14512,14513,30897,31025,
                        96561,162097,162609,170801,170865,170868,170869};
  int i = blockIdx.x * 256 + threadIdx.x;
  if (i >= WTOT) return;
  int s = 0;
  #pragma unroll
  for (int k = 1; k < 16; ++k) if (i >= offs[k]) s = k;
  int j = i - offs[s];
  if (*flag) out[i] = b2f(((const u16*)ps[s])[j]);
  else       out[i] = ((const float*)ps[s])[j];
}

// ---------------- counts of kbin ----------------
__global__ __launch_bounds__(256) void k_counts(const int* __restrict__ kbin,
                                                float* __restrict__ cnts) {
  __shared__ float s[NCC];
  int t = threadIdx.x;
  if (t < NCC) s[t] = 0.f;
  __syncthreads();
  int i = blockIdx.x * 256 + t;
  atomicAdd(&s[kbin[i]], 1.f);
  __syncthreads();
  if (t < NCC) atomicAdd(&cnts[t], s[t]);
}

// ---------------- adam-like update -> delta ----------------
__global__ __launch_bounds__(256) void k_adam(const float* __restrict__ pos,
                                              const float* __restrict__ y,
                                              float* __restrict__ m, float* __restrict__ v,
                                              float* __restrict__ delta,
                                              float ib1, float ib2) {
  int i = blockIdx.x * 256 + threadIdx.x;
  float g  = pos[i] - y[i];
  float mi = 0.9f  * m[i] + 0.1f   * g;
  float vi = 0.999f* v[i] + 0.001f * g * g;
  m[i] = mi; v[i] = vi;
  delta[i] = -0.1f * (mi * ib1) / (sqrtf(vi * ib2) + 1e-7f);
}

// ---------------- one FFT axis pass (64-pt DFT per line) ----------------
__global__ __launch_bounds__(256) void k_fft(const float* rin, const float2* cin,
                                             float2* out, int lineStride, int aStride,
                                             int bStride, float fsign) {
  __shared__ float2 lds[4][64];
  __shared__ float2 tw[64];
  int t = threadIdx.x, lane = t & 63, g = t >> 6;
  if (t < 64) {
    float ang = fsign * (-6.2831853071795864769f / 64.0f) * (float)t;
    float s, c; sincosf(ang, &s, &c);
    tw[t] = make_float2(c, s);
  }
  int line = blockIdx.x * 4 + g;
  int b = line >> 12, rem = line & 4095;
  size_t base = (size_t)b * VOL + (size_t)(rem >> 6) * aStride + (size_t)(rem & 63) * bStride;
  size_t idx = base + (size_t)lane * lineStride;
  float2 val = rin ? make_float2(rin[idx], 0.f) : cin[idx];
  lds[g][lane] = val;
  __syncthreads();
  float re = 0.f, im = 0.f;
  #pragma unroll 8
  for (int k = 0; k < 64; ++k) {
    float2 x = lds[g][k];
    float2 w = tw[(lane * k) & 63];
    re = fmaf(x.x, w.x, fmaf(-x.y, w.y, re));
    im = fmaf(x.x, w.y, fmaf( x.y, w.x, im));
  }
  out[idx] = make_float2(re, im);
}

// ---------------- |X/N^3|^2 binned by kbin ----------------
__global__ __launch_bounds__(256) void k_power(const float2* __restrict__ X,
                                               const int* __restrict__ kbin,
                                               float* __restrict__ psum) {
  __shared__ float s[NCC];
  int t = threadIdx.x;
  if (t < NCC) s[t] = 0.f;
  __syncthreads();
  int b = blockIdx.y;
  int cell = blockIdx.x * 256 + t;
  float2 v = X[(size_t)b * VOL + cell];
  const float INV = 1.0f / ((float)VOL * (float)VOL);
  float pm = (v.x * v.x + v.y * v.y) * INV;
  atomicAdd(&s[kbin[cell]], pm);
  __syncthreads();
  if (t < NCC) atomicAdd(&psum[b * NCC + t], s[t]);
}

// ---------------- conv3d (pos,delta)->8ch cell_in ----------------
__global__ __launch_bounds__(256) void k_cellin(const float* __restrict__ pos,
                                                const float* __restrict__ delta,
                                                const float* __restrict__ Win,
                                                const float* __restrict__ bin_,
                                                float* __restrict__ cellin) {
  int id = blockIdx.x * 256 + threadIdx.x;
  int z = id & 63, yy = (id >> 6) & 63, x = (id >> 12) & 63, b = id >> 18;
  float acc[8];
  #pragma unroll
  for (int c = 0; c < 8; ++c) acc[c] = bin_[c];
  #pragma unroll 1
  for (int tap = 0; tap < 27; ++tap) {
    int kd = tap / 9, kh = (tap / 3) % 3, kw = tap % 3;
    int nx = x + kd - 1, ny = yy + kh - 1, nz = z + kw - 1;
    if ((unsigned)nx >= 64u || (unsigned)ny >= 64u || (unsigned)nz >= 64u) continue;
    size_t n = (((size_t)b * 64 + nx) * 64 + ny) * 64 + nz;
    float p = pos[n], d = delta[n];
    const float* w = Win + tap * 16;
    #pragma unroll
    for (int c = 0; c < 8; ++c) acc[c] = fmaf(p, w[c], fmaf(d, w[8 + c], acc[c]));
  }
  size_t o = (size_t)id * 8;
  *(float4*)&cellin[o]     = make_float4(acc[0], acc[1], acc[2], acc[3]);
  *(float4*)&cellin[o + 4] = make_float4(acc[4], acc[5], acc[6], acc[7]);
}

// ---------------- fused ConvLSTM ----------------
__global__ __launch_bounds__(256) void k_convlstm(const float* __restrict__ cellin,
                                                  const float* __restrict__ h3p,
                                                  float* __restrict__ c3,
                                                  const float* __restrict__ Wx,
                                                  const float* __restrict__ Wh,
                                                  const float* __restrict__ b3,
                                                  float* __restrict__ h3n) {
  int id = blockIdx.x * 256 + threadIdx.x;
  int z = id & 63, yy = (id >> 6) & 63, x = (id >> 12) & 63, b = id >> 18;
  float acc[32];
  #pragma unroll
  for (int c = 0; c < 32; ++c) acc[c] = b3[c];
  #pragma unroll 1
  for (int tap = 0; tap < 27; ++tap) {
    int kd = tap / 9, kh = (tap / 3) % 3, kw = tap % 3;
    int nx = x + kd - 1, ny = yy + kh - 1, nz = z + kw - 1;
    if ((unsigned)nx >= 64u || (unsigned)ny >= 64u || (unsigned)nz >= 64u) continue;
    size_t n = ((((size_t)b * 64 + nx) * 64 + ny) * 64 + nz) * 8;
    float ci[8], hh[8];
    *(float4*)&ci[0] = *(const float4*)&cellin[n];
    *(float4*)&ci[4] = *(const float4*)&cellin[n + 4];
    *(float4*)&hh[0] = *(const float4*)&h3p[n];
    *(float4*)&hh[4] = *(const float4*)&h3p[n + 4];
    const float* wx = Wx + tap * 256;
    const float* wh = Wh + tap * 256;
    #pragma unroll
    for (int cc = 0; cc < 8; ++cc) {
      float a = ci[cc], hv = hh[cc];
      #pragma unroll
      for (int co = 0; co < 32; ++co)
        acc[co] = fmaf(a, wx[cc * 32 + co], fmaf(hv, wh[cc * 32 + co], acc[co]));
    }
  }
  size_t o = (size_t)id * 8;
  #pragma unroll
  for (int c = 0; c < 8; ++c) {
    float ig = 1.f / (1.f + expf(-acc[c]));
    float fg = 1.f / (1.f + expf(-acc[8 + c]));
    float gg = tanhf(acc[16 + c]);
    float og = 1.f / (1.f + expf(-acc[24 + c]));
    float cn = fg * c3[o + c] + ig * gg;
    c3[o + c] = cn;
    h3n[o + c] = og * tanhf(cn);
  }
}

// ---------------- conv3d h3(8ch) -> 1ch delta_poswhite ----------------
__global__ __launch_bounds__(256) void k_wout(const float* __restrict__ h3,
                                              const float* __restrict__ Wo,
                                              const float* __restrict__ bo,
                                              float* __restrict__ dpw) {
  int id = blockIdx.x * 256 + threadIdx.x;
  int z = id & 63, yy = (id >> 6) & 63, x = (id >> 12) & 63, b = id >> 18;
  float acc = bo[0];
  #pragma unroll 1
  for (int tap = 0; tap < 27; ++tap) {
    int kd = tap / 9, kh = (tap / 3) % 3, kw = tap % 3;
    int nx = x + kd - 1, ny = yy + kh - 1, nz = z + kw - 1;
    if ((unsigned)nx >= 64u || (unsigned)ny >= 64u || (unsigned)nz >= 64u) continue;
    size_t n = ((((size_t)b * 64 + nx) * 64 + ny) * 64 + nz) * 8;
    float hh[8];
    *(float4*)&hh[0] = *(const float4*)&h3[n];
    *(float4*)&hh[4] = *(const float4*)&h3[n + 4];
    const float* w = Wo + tap * 8;
    #pragma unroll
    for (int c = 0; c < 8; ++c) acc = fmaf(hh[c], w[c], acc);
  }
  dpw[id] = acc;
}

// ---------------- small dense LSTM branch: one block per batch row ----------------
__global__ __launch_bounds__(256) void k_small(const float* __restrict__ psp,
                                               const float* __restrict__ psd,
                                               const float* __restrict__ cnts,
                                               const float* __restrict__ Wd1,
                                               const float* __restrict__ bd1,
                                               const float* __restrict__ Wlx,
                                               const float* __restrict__ Wlh,
                                               const float* __restrict__ bl,
                                               const float* __restrict__ Wd2,
                                               const float* __restrict__ bd2,
                                               const float* __restrict__ Wc1,
                                               const float* __restrict__ bc1,
                                               float* __restrict__ h1, float* __restrict__ c1,
                                               float* __restrict__ psn) {
  __shared__ float lp[128], x1[128], hs[128], zz[512], lps[66];
  int t = threadIdx.x, b = blockIdx.x;
  if (t < 64) {
    lp[t]      = log10f(fmaxf(psp[b*64 + t] / cnts[t] * 8.0e6f, 1e-30f));
    lp[64 + t] = log10f(fmaxf(psd[b*64 + t] / cnts[t] * 8.0e6f, 1e-30f));
  }
  if (t < 128) hs[t] = h1[b*128 + t];
  __syncthreads();
  if (t < 128) {
    float a = bd1[t];
    for (int j = 0; j < 128; ++j) a = fmaf(lp[j], Wd1[j*128 + t], a);
    x1[t] = a;
  }
  __syncthreads();
  for (int k = t; k < 512; k += 256) {
    float a = bl[k];
    for (int u = 0; u < 128; ++u)
      a = fmaf(x1[u], Wlx[u*512 + k], fmaf(hs[u], Wlh[u*512 + k], a));
    zz[k] = a;
  }
  __syncthreads();
  if (t < 128) {
    float ig = 1.f/(1.f + expf(-zz[t]));
    float fg = 1.f/(1.f + expf(-zz[128 + t]));
    float gg = tanhf(zz[256 + t]);
    float og = 1.f/(1.f + expf(-zz[384 + t]));
    float cv = fg * c1[b*128 + t] + ig * gg;
    c1[b*128 + t] = cv;
    float hv = og * tanhf(cv);
    h1[b*128 + t] = hv; hs[t] = hv;
  }
  __syncthreads();
  if (t < 64) {
    float a = bd2[t];
    for (int u = 0; u < 128; ++u) a = fmaf(hs[u], Wd2[u*64 + t], a);
    lps[t + 1] = a;
  }
  __syncthreads();
  if (t < 64) {
    float a = fmaf(Wc1[1], lps[t + 1], bc1[0]);
    if (t > 0)  a = fmaf(Wc1[0], lps[t], a);
    if (t < 63) a = fmaf(Wc1[2], lps[t + 2], a);
    psn[b*64 + t] = expf(a);
  }
}

// ---------------- spectrum *= sqrt(ps[bin]) ----------------
__global__ __launch_bounds__(256) void k_specmul(float2* __restrict__ X,
                                                 const int* __restrict__ kbin,
                                                 const float* __restrict__ psn) {
  int t = threadIdx.x;
  int b = blockIdx.y;
  int cell = blockIdx.x * 256 + t;
  float fac = sqrtf(psn[b*64 + kbin[cell]]);
  size_t i = (size_t)b * VOL + cell;
  float2 v = X[i];
  X[i] = make_float2(v.x * fac, v.y * fac);
}

// ---------------- pos += real(ifft)/N^3 ; loss sum ----------------
__global__ __launch_bounds__(256) void k_final(const float2* __restrict__ X,
                                               float* __restrict__ pos,
                                               const float* __restrict__ xtrue,
                                               float* __restrict__ lsum) {
  __shared__ float red[256];
  int i = blockIdx.x * 256 + threadIdx.x;
  float np = pos[i] + X[i].x * (1.0f / (float)VOL);
  pos[i] = np;
  float d = xtrue[i] - np;
  red[threadIdx.x] = d * d;
  __syncthreads();
  for (int s = 128; s > 0; s >>= 1) {
    if (threadIdx.x < s) red[threadIdx.x] += red[threadIdx.x + s];
    __syncthreads();
  }
  if (threadIdx.x == 0) atomicAdd(lsum, red[0]);
}

// ---------------- pos -> out (dtype-flagged) ----------------
__global__ __launch_bounds__(256) void k_out(const float* __restrict__ pos, void* __restrict__ outp,
                                             size_t eoff, const int* __restrict__ flag) {
  size_t i = (size_t)blockIdx.x * 256 + threadIdx.x;
  if (*flag) ((u16*)outp)[eoff + i] = f2b(pos[i]);
  else       ((float*)outp)[eoff + i] = pos[i];
}

__global__ void k_loss(const float* __restrict__ lsum, void* __restrict__ outp,
                       const int* __restrict__ flag) {
  float l = lsum[0] * (1.0f / (float)TOT);
  if (*flag) ((u16*)outp)[TOT] = f2b(l);
  else       ((float*)outp)[TOT] = l;
}

__global__ void k_sent(u16* __restrict__ outp) { outp[0] = f2b(1000.0f); }

extern "C" void kernel_launch(void* const* d_in, const int* in_sizes, int n_in,
                              void* d_out, int out_size, void* d_ws, size_t ws_size,
                              hipStream_t stream) {
  const void* x_init = d_in[0];
  const void* y      = d_in[1];
  const void* x_true = d_in[2];
  const int*  kbin   = (const int*)d_in[3];

  // pick largest batch-slice that fits ws
  int nbs = 0;
  for (int cand = 8; cand >= 1; cand >>= 1) {
    size_t n1 = (size_t)cand * VOL;
    size_t need = (n1 * 38 + 170880 + (size_t)cand * (3*64 + 2*128) + 64 + 8 + 64) * sizeof(float);
    if (need <= ws_size) { nbs = cand; break; }
  }
  if (nbs == 0) { k_sent<<<1, 1, 0, stream>>>((u16*)d_out); return; }

  size_t n1 = (size_t)nbs * VOL;
  float* ws   = (float*)d_ws;
  float* pos  = ws;
  float* m    = pos + n1;
  float* v    = m + n1;
  float* dpw  = v + n1;             // delta / delta_poswhite
  float* yf   = dpw + n1;
  float* xtf  = yf + n1;
  float* c3   = xtf + n1;           // n1*8
  float* h3a  = c3 + n1*8;          // n1*8
  float* h3b  = h3a + n1*8;         // n1*8
  float* big  = h3b + n1*8;         // n1*8 : cell_in f32 OR cbuf float2
  float* wbuf = big + n1*8;         // 170880 (padded)
  float* psp  = wbuf + 170880;
  float* psd  = psp + (size_t)nbs*64;
  float* psn  = psd + (size_t)nbs*64;
  float* cnts = psn + (size_t)nbs*64;
  float* lsum = cnts + 64;          // 8
  float* h1   = lsum + 8;           // nbs*128
  float* c1   = h1 + (size_t)nbs*128;
  int*   flag = (int*)(c1 + (size_t)nbs*128);

  // wbuf offsets
  float* Win_f = wbuf + 0;    float* bin_f = wbuf + 432;
  float* Wx_f  = wbuf + 440;  float* Wh_f  = wbuf + 7352;
  float* b3_f  = wbuf + 14264;float* Wo_f  = wbuf + 14296;
  float* bo_f  = wbuf + 14512;float* Wd1_f = wbuf + 14513;
  float* bd1_f = wbuf + 30897;float* Wlx_f = wbuf + 31025;
  float* Wlh_f = wbuf + 96561;float* bl_f  = wbuf + 162097;
  float* Wd2_f = wbuf + 162609;float* bd2_f= wbuf + 170801;
  float* Wc1_f = wbuf + 170865;float* bc1_f= wbuf + 170868;

  const int CB = (int)(n1 / 256);
  float2* cb = (float2*)big;

  k_sniff<<<1, 256, 0, stream>>>((const u16*)x_init, flag);
  k_cvtall<<<(WTOT + 255) / 256, 256, 0, stream>>>(
      d_in[4], d_in[5], d_in[6], d_in[7], d_in[8], d_in[9], d_in[10], d_in[11],
      d_in[12], d_in[13], d_in[14], d_in[15], d_in[16], d_in[17], d_in[18], d_in[19],
      wbuf, flag);
  hipMemsetAsync(cnts, 0, 64 * 4, stream);
  hipMemsetAsync(lsum, 0, 8 * 4, stream);
  k_counts<<<VOL / 256, 256, 0, stream>>>(kbin, cnts);

  for (int b0 = 0; b0 < NB; b0 += nbs) {
    hipMemsetAsync(m, 0, n1 * 4, stream);
    hipMemsetAsync(v, 0, n1 * 4, stream);
    hipMemsetAsync(c3, 0, n1 * 8 * 4, stream);
    hipMemsetAsync(h3a, 0, n1 * 8 * 4, stream);
    hipMemsetAsync(h1, 0, (size_t)nbs * 256 * 4, stream);
    k_cvt<<<CB, 256, 0, stream>>>(x_init, (size_t)b0 * VOL, pos, flag);
    k_cvt<<<CB, 256, 0, stream>>>(y,      (size_t)b0 * VOL, yf, flag);
    k_cvt<<<CB, 256, 0, stream>>>(x_true, (size_t)b0 * VOL, xtf, flag);

    float* h3p = h3a;
    float* h3n = h3b;
    for (int t = 1; t <= 4; ++t) {
      float ib1 = (float)(1.0 / (1.0 - pow(0.9, (double)t)));
      float ib2 = (float)(1.0 / (1.0 - pow(0.999, (double)t)));
      k_adam<<<CB, 256, 0, stream>>>(pos, yf, m, v, dpw, ib1, ib2);

      hipMemsetAsync(psp, 0, (size_t)nbs * 64 * 4, stream);
      k_fft<<<nbs * 1024, 256, 0, stream>>>(pos, nullptr, cb, 1, 4096, 64, 1.f);
      k_fft<<<nbs * 1024, 256, 0, stream>>>(nullptr, cb, cb, 64, 4096, 1, 1.f);
      k_fft<<<nbs * 1024, 256, 0, stream>>>(nullptr, cb, cb, 4096, 64, 1, 1.f);
      k_power<<<dim3(VOL / 256, nbs), 256, 0, stream>>>(cb, kbin, psp);

      hipMemsetAsync(psd, 0, (size_t)nbs * 64 * 4, stream);
      k_fft<<<nbs * 1024, 256, 0, stream>>>(dpw, nullptr, cb, 1, 4096, 64, 1.f);
      k_fft<<<nbs * 1024, 256, 0, stream>>>(nullptr, cb, cb, 64, 4096, 1, 1.f);
      k_fft<<<nbs * 1024, 256, 0, stream>>>(nullptr, cb, cb, 4096, 64, 1, 1.f);
      k_power<<<dim3(VOL / 256, nbs), 256, 0, stream>>>(cb, kbin, psd);

      k_cellin<<<CB, 256, 0, stream>>>(pos, dpw, Win_f, bin_f, big);
      k_convlstm<<<CB, 256, 0, stream>>>(big, h3p, c3, Wx_f, Wh_f, b3_f, h3n);
      k_wout<<<CB, 256, 0, stream>>>(h3n, Wo_f, bo_f, dpw);

      k_small<<<nbs, 256, 0, stream>>>(psp, psd, cnts, Wd1_f, bd1_f, Wlx_f, Wlh_f, bl_f,
                                       Wd2_f, bd2_f, Wc1_f, bc1_f, h1, c1, psn);

      k_fft<<<nbs * 1024, 256, 0, stream>>>(dpw, nullptr, cb, 1, 4096, 64, 1.f);
      k_fft<<<nbs * 1024, 256, 0, stream>>>(nullptr, cb, cb, 64, 4096, 1, 1.f);
      k_fft<<<nbs * 1024, 256, 0, stream>>>(nullptr, cb, cb, 4096, 64, 1, 1.f);
      k_specmul<<<dim3(VOL / 256, nbs), 256, 0, stream>>>(cb, kbin, psn);
      k_fft<<<nbs * 1024, 256, 0, stream>>>(nullptr, cb, cb, 1, 4096, 64, -1.f);
      k_fft<<<nbs * 1024, 256, 0, stream>>>(nullptr, cb, cb, 64, 4096, 1, -1.f);
      k_fft<<<nbs * 1024, 256, 0, stream>>>(nullptr, cb, cb, 4096, 64, 1, -1.f);

      k_final<<<CB, 256, 0, stream>>>(cb, pos, xtf, lsum);

      float* tmp = h3p; h3p = h3n; h3n = tmp;
    }
    k_out<<<CB, 256, 0, stream>>>(pos, d_out, (size_t)b0 * VOL, flag);
  }
  k_loss<<<1, 1, 0, stream>>>(lsum, d_out, flag);
}

// Round 4
// 3948.664 us; speedup vs baseline: 1.5290x; 1.5290x over previous
//
#include <hip/hip_runtime.h>
#include <math.h>

#define NCC 64
#define NB 8
#define VOL (NCC*NCC*NCC)      // 262144 = 2^18
#define TOT (NB*VOL)           // 2097152
#define WTOT 170869            // total weight elements
#define PI2 6.2831853071795864769f

typedef unsigned short u16;
typedef __bf16 bf16x8 __attribute__((ext_vector_type(8)));
typedef float f32x16 __attribute__((ext_vector_type(16)));

__device__ __forceinline__ float b2f(u16 h){ return __uint_as_float(((unsigned)h)<<16); }
__device__ __forceinline__ u16 f2b(float f){
  unsigned u = __float_as_uint(f);
  unsigned r = (u + 0x7FFFu + ((u>>16)&1u)) >> 16;
  return (u16)r;
}

// ---------------- dtype sniff: 1 = bf16, 0 = f32 ----------------
__global__ __launch_bounds__(256) void k_sniff(const u16* __restrict__ x, int* __restrict__ flag) {
  __shared__ int cnt;
  if (threadIdx.x == 0) cnt = 0;
  __syncthreads();
  int sane = 0;
  for (int i = threadIdx.x; i < 1024; i += 256) {
    u16 h = x[2 * i];
    int e = (h >> 7) & 0xFF;
    if (h == 0 || (e >= 0x68 && e <= 0x8F)) sane++;
  }
  atomicAdd(&cnt, sane);
  __syncthreads();
  if (threadIdx.x == 0) flag[0] = (cnt >= 768) ? 1 : 0;
}

// ---------------- generic slice convert ----------------
__global__ __launch_bounds__(256) void k_cvt(const void* __restrict__ in, size_t eoff,
                                             float* __restrict__ out, const int* __restrict__ flag) {
  size_t i = (size_t)blockIdx.x * 256 + threadIdx.x;
  if (*flag) out[i] = b2f(((const u16*)in)[eoff + i]);
  else       out[i] = ((const float*)in)[eoff + i];
}

// ---------------- all-weights convert to f32 ----------------
__global__ __launch_bounds__(256) void k_cvtall(
    const void* s0, const void* s1, const void* s2, const void* s3,
    const void* s4, const void* s5, const void* s6, const void* s7,
    const void* s8, const void* s9, const void* s10, const void* s11,
    const void* s12, const void* s13, const void* s14, const void* s15,
    float* __restrict__ out, const int* __restrict__ flag) {
  const void* ps[16] = {s0,s1,s2,s3,s4,s5,s6,s7,s8,s9,s10,s11,s12,s13,s14,s15};
  const int offs[17] = {0,432,440,7352,14264,14296,14512,14513,30897,31025,
                        96561,162097,162609,170801,170865,170868,170869};
  int i = blockIdx.x * 256 + threadIdx.x;
  if (i >= WTOT) return;
  int s = 0;
  #pragma unroll
  for (int k = 1; k < 16; ++k) if (i >= offs[k]) s = k;
  int j = i - offs[s];
  if (*flag) out[i] = b2f(((const u16*)ps[s])[j]);
  else       out[i] = ((const float*)ps[s])[j];
}

// ---------------- fused MFMA weight build: Wf[27][32][16] bf16 ----------------
__global__ __launch_bounds__(256) void k_mkwf(const void* __restrict__ Wx, const void* __restrict__ Wh,
                                              const int* __restrict__ flag, u16* __restrict__ Wf) {
  int i = blockIdx.x * 256 + threadIdx.x;   // 13824
  if (i >= 13824) return;
  int k = i & 15, co = (i >> 4) & 31, tap = i >> 9;
  int src = tap * 256 + (k & 7) * 32 + co;
  const void* P = (k < 8) ? Wx : Wh;
  u16 val;
  if (*flag) val = ((const u16*)P)[src];
  else       val = f2b(((const float*)P)[src]);
  Wf[i] = val;
}

// ---------------- counts of kbin ----------------
__global__ __launch_bounds__(256) void k_counts(const int* __restrict__ kbin,
                                                float* __restrict__ cnts) {
  __shared__ float s[NCC];
  int t = threadIdx.x;
  if (t < NCC) s[t] = 0.f;
  __syncthreads();
  int i = blockIdx.x * 256 + t;
  atomicAdd(&s[kbin[i]], 1.f);
  __syncthreads();
  if (t < NCC) atomicAdd(&cnts[t], s[t]);
}

// ---------------- adam-like update -> delta ----------------
__global__ __launch_bounds__(256) void k_adam(const float* __restrict__ pos,
                                              const float* __restrict__ y,
                                              float* __restrict__ m, float* __restrict__ v,
                                              float* __restrict__ delta,
                                              float ib1, float ib2, int first) {
  int i = blockIdx.x * 256 + threadIdx.x;
  float g  = pos[i] - y[i];
  float mi, vi;
  if (first) { mi = 0.1f * g; vi = 0.001f * g * g; }
  else { mi = 0.9f * m[i] + 0.1f * g; vi = 0.999f * v[i] + 0.001f * g * g; }
  m[i] = mi; v[i] = vi;
  delta[i] = -0.1f * (mi * ib1) / (sqrtf(vi * ib2) + 1e-7f);
}

// ---------------- FFT: z & y forward of each (b,x) plane, real input ----------------
__global__ __launch_bounds__(256) void k_fft_zy(const float* __restrict__ rin,
                                                float2* __restrict__ cout) {
  __shared__ float rb[64][65];
  __shared__ float2 pl[64][65];
  __shared__ float2 tw[64];
  int t = threadIdx.x;
  if (t < 64) { float s, c; sincosf(-(PI2/64.f)*t, &s, &c); tw[t] = make_float2(c, s); }
  int b = blockIdx.x >> 6, x = blockIdx.x & 63;
  const float* src = rin + (size_t)(b*64 + x) * 4096;
  for (int i = 0; i < 16; ++i) { int idx = t + 256*i; rb[idx>>6][idx&63] = src[idx]; }
  __syncthreads();
  int zo = t & 63, g = t >> 6;
  float orr[16], oii[16];
  #pragma unroll 1
  for (int j = 0; j < 16; ++j) {               // z-DFT (real input)
    int yy = g*16 + j;
    float re = 0.f, im = 0.f;
    #pragma unroll 8
    for (int k = 0; k < 64; ++k) {
      float vv = rb[yy][k];
      float2 w = tw[(zo*k)&63];
      re = fmaf(vv, w.x, re);
      im = fmaf(vv, w.y, im);
    }
    orr[j] = re; oii[j] = im;
  }
  __syncthreads();
  for (int j = 0; j < 16; ++j) { int yy = g*16+j; pl[yy][zo] = make_float2(orr[j], oii[j]); }
  __syncthreads();
  int z = t & 63;
  #pragma unroll 1
  for (int j = 0; j < 16; ++j) {               // y-DFT (complex)
    int yo = g*16 + j;
    float re = 0.f, im = 0.f;
    #pragma unroll 8
    for (int k = 0; k < 64; ++k) {
      float2 a = pl[k][z];
      float2 w = tw[(yo*k)&63];
      re = fmaf(a.x, w.x, fmaf(-a.y, w.y, re));
      im = fmaf(a.x, w.y, fmaf( a.y, w.x, im));
    }
    orr[j] = re; oii[j] = im;
  }
  float2* dst = cout + (size_t)(b*64 + x) * 4096;
  for (int j = 0; j < 16; ++j) { int yo = g*16+j; dst[yo*64 + z] = make_float2(orr[j], oii[j]); }
}

// ---------------- FFT x forward + power binning (no X writeback) ----------------
__global__ __launch_bounds__(256) void k_fft_x_pow(const float2* __restrict__ cin,
                                                   const int* __restrict__ kb,
                                                   float* __restrict__ psum) {
  __shared__ float2 pl[64][65];
  __shared__ float2 tw[64];
  __shared__ float pb[64];
  int t = threadIdx.x;
  if (t < 64) { float s, c; sincosf(-(PI2/64.f)*t, &s, &c); tw[t] = make_float2(c, s); pb[t] = 0.f; }
  int b = blockIdx.x >> 6, y = blockIdx.x & 63;
  for (int i = 0; i < 16; ++i) {
    int idx = t + 256*i; int xx = idx >> 6, z = idx & 63;
    pl[xx][z] = cin[((size_t)(b*64 + xx)*64 + y)*64 + z];
  }
  __syncthreads();
  int z = t & 63, g = t >> 6;
  const float INV = 1.0f / ((float)VOL * (float)VOL);
  #pragma unroll 1
  for (int j = 0; j < 16; ++j) {
    int xo = g*16 + j;
    float re = 0.f, im = 0.f;
    #pragma unroll 8
    for (int k = 0; k < 64; ++k) {
      float2 a = pl[k][z];
      float2 w = tw[(xo*k)&63];
      re = fmaf(a.x, w.x, fmaf(-a.y, w.y, re));
      im = fmaf(a.x, w.y, fmaf( a.y, w.x, im));
    }
    float pm = (re*re + im*im) * INV;
    int bin = kb[(xo*64 + y)*64 + z];
    atomicAdd(&pb[bin], pm);
  }
  __syncthreads();
  if (t < 64) atomicAdd(&psum[b*64 + t], pb[t]);
}

// ---------------- FFT x: fwd, *= sqrt(ps[bin]), inverse (in-place on cb) ----------------
__global__ __launch_bounds__(256) void k_fft_x_filt(float2* __restrict__ cb,
                                                    const int* __restrict__ kb,
                                                    const float* __restrict__ psn) {
  __shared__ float2 pl[64][65];
  __shared__ float2 tw[64];
  int t = threadIdx.x;
  if (t < 64) { float s, c; sincosf(-(PI2/64.f)*t, &s, &c); tw[t] = make_float2(c, s); }
  int b = blockIdx.x >> 6, y = blockIdx.x & 63;
  for (int i = 0; i < 16; ++i) {
    int idx = t + 256*i; int xx = idx >> 6, z = idx & 63;
    pl[xx][z] = cb[((size_t)(b*64 + xx)*64 + y)*64 + z];
  }
  __syncthreads();
  int z = t & 63, g = t >> 6;
  float orr[16], oii[16];
  #pragma unroll 1
  for (int j = 0; j < 16; ++j) {               // forward x
    int xo = g*16 + j;
    float re = 0.f, im = 0.f;
    #pragma unroll 8
    for (int k = 0; k < 64; ++k) {
      float2 a = pl[k][z];
      float2 w = tw[(xo*k)&63];
      re = fmaf(a.x, w.x, fmaf(-a.y, w.y, re));
      im = fmaf(a.x, w.y, fmaf( a.y, w.x, im));
    }
    float fac = sqrtf(psn[b*64 + kb[(xo*64 + y)*64 + z]]);
    orr[j] = re * fac; oii[j] = im * fac;
  }
  __syncthreads();
  for (int j = 0; j < 16; ++j) { int xo = g*16+j; pl[xo][z] = make_float2(orr[j], oii[j]); }
  __syncthreads();
  #pragma unroll 1
  for (int j = 0; j < 16; ++j) {               // inverse x (conj twiddle)
    int xn = g*16 + j;
    float re = 0.f, im = 0.f;
    #pragma unroll 8
    for (int k = 0; k < 64; ++k) {
      float2 a = pl[k][z];
      float2 w = tw[(xn*k)&63];
      re = fmaf(a.x, w.x, fmaf( a.y, w.y, re));
      im = fmaf(a.y, w.x, fmaf(-a.x, w.y, im));
    }
    orr[j] = re; oii[j] = im;
  }
  for (int j = 0; j < 16; ++j) {
    int xn = g*16 + j;
    cb[((size_t)(b*64 + xn)*64 + y)*64 + z] = make_float2(orr[j], oii[j]);
  }
}

// ---------------- FFT: inverse y & z, pos += re/VOL, loss ----------------
__global__ __launch_bounds__(256) void k_fft_zy_inv(const float2* __restrict__ cin,
                                                    float* __restrict__ pos,
                                                    const float* __restrict__ xtf,
                                                    float* __restrict__ lsum) {
  __shared__ float2 pl[64][65];
  __shared__ float2 tw[64];
  __shared__ float red[256];
  int t = threadIdx.x;
  if (t < 64) { float s, c; sincosf(-(PI2/64.f)*t, &s, &c); tw[t] = make_float2(c, s); }
  int b = blockIdx.x >> 6, x = blockIdx.x & 63;
  const float2* src = cin + (size_t)(b*64 + x) * 4096;
  for (int i = 0; i < 16; ++i) { int idx = t + 256*i; pl[idx>>6][idx&63] = src[idx]; }
  __syncthreads();
  int z = t & 63, g = t >> 6;
  float orr[16], oii[16];
  #pragma unroll 1
  for (int j = 0; j < 16; ++j) {               // inverse y
    int yo = g*16 + j;
    float re = 0.f, im = 0.f;
    #pragma unroll 8
    for (int k = 0; k < 64; ++k) {
      float2 a = pl[k][z];
      float2 w = tw[(yo*k)&63];
      re = fmaf(a.x, w.x, fmaf( a.y, w.y, re));
      im = fmaf(a.y, w.x, fmaf(-a.x, w.y, im));
    }
    orr[j] = re; oii[j] = im;
  }
  __syncthreads();
  for (int j = 0; j < 16; ++j) { int yo = g*16+j; pl[yo][z] = make_float2(orr[j], oii[j]); }
  __syncthreads();
  int zo = t & 63;
  float lacc = 0.f;
  float* pdst = pos + (size_t)(b*64 + x) * 4096;
  const float* xt = xtf + (size_t)(b*64 + x) * 4096;
  #pragma unroll 1
  for (int j = 0; j < 16; ++j) {               // inverse z, real part only
    int yy = g*16 + j;
    float re = 0.f;
    #pragma unroll 8
    for (int k = 0; k < 64; ++k) {
      float2 a = pl[yy][k];
      float2 w = tw[(zo*k)&63];
      re = fmaf(a.x, w.x, fmaf(a.y, w.y, re));
    }
    int idx = yy*64 + zo;
    float np = pdst[idx] + re * (1.0f/(float)VOL);
    pdst[idx] = np;
    float d = xt[idx] - np;
    lacc = fmaf(d, d, lacc);
  }
  red[t] = lacc; __syncthreads();
  for (int s = 128; s > 0; s >>= 1) { if (t < s) red[t] += red[t+s]; __syncthreads(); }
  if (t == 0) atomicAdd(lsum, red[0]);
}

// ---------------- conv3d (pos,delta)->8ch cell_in, bf16 out into combined buf ----------------
__global__ __launch_bounds__(256) void k_cellin(const float* __restrict__ pos,
                                                const float* __restrict__ delta,
                                                const float* __restrict__ Win,
                                                const float* __restrict__ binf,
                                                u16* __restrict__ bufC) {
  int id = blockIdx.x * 256 + threadIdx.x;
  int z = id & 63, yy = (id >> 6) & 63, x = (id >> 12) & 63, b = id >> 18;
  float acc[8];
  #pragma unroll
  for (int c = 0; c < 8; ++c) acc[c] = binf[c];
  #pragma unroll 1
  for (int tap = 0; tap < 27; ++tap) {
    int kd = tap / 9, kh = (tap / 3) % 3, kw = tap % 3;
    int nx = x + kd - 1, ny = yy + kh - 1, nz = z + kw - 1;
    if ((unsigned)nx >= 64u || (unsigned)ny >= 64u || (unsigned)nz >= 64u) continue;
    size_t n = (((size_t)b * 64 + nx) * 64 + ny) * 64 + nz;
    float p = pos[n], d = delta[n];
    const float* w = Win + tap * 16;
    #pragma unroll
    for (int c = 0; c < 8; ++c) acc[c] = fmaf(p, w[c], fmaf(d, w[8 + c], acc[c]));
  }
  u16 hh[8];
  #pragma unroll
  for (int c = 0; c < 8; ++c) hh[c] = f2b(acc[c]);
  *(uint4*)(bufC + (size_t)id * 16) = *(uint4*)hh;
}

// ---------------- MFMA ConvLSTM ----------------
__global__ __launch_bounds__(256) void k_clstm(const u16* __restrict__ bufC,
                                               u16* __restrict__ bufN,
                                               float* __restrict__ c3,
                                               const u16* __restrict__ Wf,
                                               const float* __restrict__ b3f) {
  __shared__ float zl[4][32][33];
  int t = threadIdx.x;
  int wv = t >> 6, l = t & 63, ln = l & 31, hi = l >> 5;
  int bid = blockIdx.x;
  int ypair = bid & 31, x = (bid >> 5) & 63, b = bid >> 11;
  int y = ypair * 2 + (wv >> 1);
  int z0 = (wv & 1) * 32;
  bf16x8 Bfr[27];
  #pragma unroll
  for (int tap = 0; tap < 27; ++tap) {
    uint4 w = *(const uint4*)(Wf + ((tap * 32 + ln) * 16 + hi * 8));
    Bfr[tap] = __builtin_bit_cast(bf16x8, w);
  }
  f32x16 acc;
  #pragma unroll
  for (int r = 0; r < 16; ++r) acc[r] = 0.f;
  int z = z0 + ln;
  #pragma unroll
  for (int tap = 0; tap < 27; ++tap) {
    int dx = tap / 9 - 1, dy = (tap / 3) % 3 - 1, dz = tap % 3 - 1;
    int nx = x + dx, ny = y + dy, nz = z + dz;
    bf16x8 afr = __builtin_bit_cast(bf16x8, make_uint4(0, 0, 0, 0));
    if ((unsigned)nx < 64u && (unsigned)ny < 64u && (unsigned)nz < 64u) {
      size_t vox = (((size_t)b * 64 + nx) * 64 + ny) * 64 + nz;
      uint4 a = *(const uint4*)(bufC + vox * 16 + hi * 8);
      afr = __builtin_bit_cast(bf16x8, a);
    }
    acc = __builtin_amdgcn_mfma_f32_32x32x16_bf16(afr, Bfr[tap], acc, 0, 0, 0);
  }
  float bz = b3f[ln];
  #pragma unroll
  for (int r = 0; r < 16; ++r) {
    int row = (r & 3) + 8 * (r >> 2) + 4 * hi;
    zl[wv][row][ln] = acc[r] + bz;
  }
  __syncthreads();
  int m = ln;
  size_t vox = (((size_t)b * 64 + x) * 64 + y) * 64 + z0 + m;
  float4 co = *(float4*)(c3 + vox * 8 + hi * 4);
  float cold[4] = {co.x, co.y, co.z, co.w};
  float cn[4]; u16 hout[4];
  #pragma unroll
  for (int q = 0; q < 4; ++q) {
    int cc = hi * 4 + q;
    float zi = zl[wv][m][cc];
    float zf = zl[wv][m][cc + 8];
    float zg = zl[wv][m][cc + 16];
    float zo_ = zl[wv][m][cc + 24];
    float ig = 1.f / (1.f + expf(-zi));
    float fg = 1.f / (1.f + expf(-zf));
    float gg = tanhf(zg);
    float og = 1.f / (1.f + expf(-zo_));
    cn[q] = fg * cold[q] + ig * gg;
    hout[q] = f2b(og * tanhf(cn[q]));
  }
  *(float4*)(c3 + vox * 8 + hi * 4) = make_float4(cn[0], cn[1], cn[2], cn[3]);
  *(uint2*)(bufN + vox * 16 + 8 + hi * 4) = *(uint2*)hout;
}

// ---------------- conv3d h3(8ch bf16) -> 1ch delta_poswhite ----------------
__global__ __launch_bounds__(256) void k_wout(const u16* __restrict__ bufN,
                                              const float* __restrict__ Wo,
                                              const float* __restrict__ bo,
                                              float* __restrict__ dpw) {
  int id = blockIdx.x * 256 + threadIdx.x;
  int z = id & 63, yy = (id >> 6) & 63, x = (id >> 12) & 63, b = id >> 18;
  float acc = bo[0];
  #pragma unroll 1
  for (int tap = 0; tap < 27; ++tap) {
    int kd = tap / 9, kh = (tap / 3) % 3, kw = tap % 3;
    int nx = x + kd - 1, ny = yy + kh - 1, nz = z + kw - 1;
    if ((unsigned)nx >= 64u || (unsigned)ny >= 64u || (unsigned)nz >= 64u) continue;
    size_t n = (((size_t)b * 64 + nx) * 64 + ny) * 64 + nz;
    uint4 a = *(const uint4*)(bufN + n * 16 + 8);
    const u16* hp = (const u16*)&a;
    const float* w = Wo + tap * 8;
    #pragma unroll
    for (int c = 0; c < 8; ++c) acc = fmaf(b2f(hp[c]), w[c], acc);
  }
  dpw[id] = acc;
}

// ---------------- small dense LSTM branch: one block per batch row ----------------
__global__ __launch_bounds__(256) void k_small(const float* __restrict__ psp,
                                               const float* __restrict__ psd,
                                               const float* __restrict__ cnts,
                                               const float* __restrict__ Wd1,
                                               const float* __restrict__ bd1,
                                               const float* __restrict__ Wlx,
                                               const float* __restrict__ Wlh,
                                               const float* __restrict__ bl,
                                               const float* __restrict__ Wd2,
                                               const float* __restrict__ bd2,
                                               const float* __restrict__ Wc1,
                                               const float* __restrict__ bc1,
                                               float* __restrict__ h1, float* __restrict__ c1,
                                               float* __restrict__ psn) {
  __shared__ float lp[128], x1[128], hs[128], zz[512], lps[66];
  int t = threadIdx.x, b = blockIdx.x;
  if (t < 64) {
    lp[t]      = log10f(fmaxf(psp[b*64 + t] / cnts[t] * 8.0e6f, 1e-30f));
    lp[64 + t] = log10f(fmaxf(psd[b*64 + t] / cnts[t] * 8.0e6f, 1e-30f));
  }
  if (t < 128) hs[t] = h1[b*128 + t];
  __syncthreads();
  if (t < 128) {
    float a = bd1[t];
    for (int j = 0; j < 128; ++j) a = fmaf(lp[j], Wd1[j*128 + t], a);
    x1[t] = a;
  }
  __syncthreads();
  for (int k = t; k < 512; k += 256) {
    float a = bl[k];
    for (int u = 0; u < 128; ++u)
      a = fmaf(x1[u], Wlx[u*512 + k], fmaf(hs[u], Wlh[u*512 + k], a));
    zz[k] = a;
  }
  __syncthreads();
  if (t < 128) {
    float ig = 1.f/(1.f + expf(-zz[t]));
    float fg = 1.f/(1.f + expf(-zz[128 + t]));
    float gg = tanhf(zz[256 + t]);
    float og = 1.f/(1.f + expf(-zz[384 + t]));
    float cv = fg * c1[b*128 + t] + ig * gg;
    c1[b*128 + t] = cv;
    float hv = og * tanhf(cv);
    h1[b*128 + t] = hv; hs[t] = hv;
  }
  __syncthreads();
  if (t < 64) {
    float a = bd2[t];
    for (int u = 0; u < 128; ++u) a = fmaf(hs[u], Wd2[u*64 + t], a);
    lps[t + 1] = a;
  }
  __syncthreads();
  if (t < 64) {
    float a = fmaf(Wc1[1], lps[t + 1], bc1[0]);
    if (t > 0)  a = fmaf(Wc1[0], lps[t], a);
    if (t < 63) a = fmaf(Wc1[2], lps[t + 2], a);
    psn[b*64 + t] = expf(a);
  }
}

// ---------------- pos -> out ----------------
__global__ __launch_bounds__(256) void k_out(const float* __restrict__ pos, void* __restrict__ outp,
                                             size_t eoff, const int* __restrict__ flag) {
  size_t i = (size_t)blockIdx.x * 256 + threadIdx.x;
  if (*flag) ((u16*)outp)[eoff + i] = f2b(pos[i]);
  else       ((float*)outp)[eoff + i] = pos[i];
}

__global__ void k_loss(const float* __restrict__ lsum, void* __restrict__ outp,
                       const int* __restrict__ flag) {
  float l = lsum[0] * (1.0f / (float)TOT);
  if (*flag) ((u16*)outp)[TOT] = f2b(l);
  else       ((float*)outp)[TOT] = l;
}

__global__ void k_sent(u16* __restrict__ outp) { outp[0] = f2b(1000.0f); }

extern "C" void kernel_launch(void* const* d_in, const int* in_sizes, int n_in,
                              void* d_out, int out_size, void* d_ws, size_t ws_size,
                              hipStream_t stream) {
  const void* x_init = d_in[0];
  const void* y      = d_in[1];
  const void* x_true = d_in[2];
  const int*  kbin   = (const int*)d_in[3];

  int nbs = 0;
  for (int cand = 8; cand >= 1; cand >>= 1) {
    size_t n1c = (size_t)cand * VOL;
    size_t need = (n1c * 32 + 171008 + 6912 + (size_t)cand * (3*64 + 2*128) + 64 + 8 + 64) * sizeof(float);
    if (need <= ws_size) { nbs = cand; break; }
  }
  if (nbs == 0) { k_sent<<<1, 1, 0, stream>>>((u16*)d_out); return; }

  size_t n1 = (size_t)nbs * VOL;
  float* ws   = (float*)d_ws;
  float* pos  = ws;
  float* m    = pos + n1;
  float* v    = m + n1;
  float* dpw  = v + n1;
  float* yf   = dpw + n1;
  float* xtf  = yf + n1;
  float* c3   = xtf + n1;             // 8n1
  float* cbf  = c3 + n1*8;            // 2n1 (float2)
  u16*  bufA  = (u16*)(cbf + n1*2);   // n1*16 u16
  u16*  bufB  = bufA + n1*16;
  float* wbuf = (float*)(bufB + n1*16);  // 171008 f32
  u16*  Wf    = (u16*)(wbuf + 171008);   // 13824 u16 (6912 f32 slots)
  float* psp  = wbuf + 171008 + 6912;
  float* psd  = psp + (size_t)nbs*64;
  float* psn  = psd + (size_t)nbs*64;
  float* cnts = psn + (size_t)nbs*64;
  float* lsum = cnts + 64;            // 8
  float* h1   = lsum + 8;
  float* c1   = h1 + (size_t)nbs*128;
  int*   flag = (int*)(c1 + (size_t)nbs*128);

  float* Win_f = wbuf + 0;     float* bin_f = wbuf + 432;
  float* b3_f  = wbuf + 14264; float* Wo_f  = wbuf + 14296;
  float* bo_f  = wbuf + 14512; float* Wd1_f = wbuf + 14513;
  float* bd1_f = wbuf + 30897; float* Wlx_f = wbuf + 31025;
  float* Wlh_f = wbuf + 96561; float* bl_f  = wbuf + 162097;
  float* Wd2_f = wbuf + 162609; float* bd2_f = wbuf + 170801;
  float* Wc1_f = wbuf + 170865; float* bc1_f = wbuf + 170868;

  const int CB = (int)(n1 / 256);
  float2* cb = (float2*)cbf;

  k_sniff<<<1, 256, 0, stream>>>((const u16*)x_init, flag);
  k_cvtall<<<(WTOT + 255) / 256, 256, 0, stream>>>(
      d_in[4], d_in[5], d_in[6], d_in[7], d_in[8], d_in[9], d_in[10], d_in[11],
      d_in[12], d_in[13], d_in[14], d_in[15], d_in[16], d_in[17], d_in[18], d_in[19],
      wbuf, flag);
  k_mkwf<<<54, 256, 0, stream>>>(d_in[6], d_in[7], flag, Wf);
  hipMemsetAsync(cnts, 0, 64 * 4, stream);
  hipMemsetAsync(lsum, 0, 8 * 4, stream);
  k_counts<<<VOL / 256, 256, 0, stream>>>(kbin, cnts);

  for (int b0 = 0; b0 < NB; b0 += nbs) {
    hipMemsetAsync(c3, 0, n1 * 8 * 4, stream);
    hipMemsetAsync(bufA, 0, n1 * 32, stream);
    hipMemsetAsync(h1, 0, (size_t)nbs * 256 * 4, stream);
    k_cvt<<<CB, 256, 0, stream>>>(x_init, (size_t)b0 * VOL, pos, flag);
    k_cvt<<<CB, 256, 0, stream>>>(y,      (size_t)b0 * VOL, yf, flag);
    k_cvt<<<CB, 256, 0, stream>>>(x_true, (size_t)b0 * VOL, xtf, flag);

    u16* bufC = bufA;
    u16* bufN = bufB;
    for (int t = 1; t <= 4; ++t) {
      float ib1 = (float)(1.0 / (1.0 - pow(0.9, (double)t)));
      float ib2 = (float)(1.0 / (1.0 - pow(0.999, (double)t)));
      k_adam<<<CB, 256, 0, stream>>>(pos, yf, m, v, dpw, ib1, ib2, t == 1);

      hipMemsetAsync(psp, 0, (size_t)nbs * 64 * 4, stream);
      k_fft_zy<<<nbs * 64, 256, 0, stream>>>(pos, cb);
      k_fft_x_pow<<<nbs * 64, 256, 0, stream>>>(cb, kbin, psp);

      hipMemsetAsync(psd, 0, (size_t)nbs * 64 * 4, stream);
      k_fft_zy<<<nbs * 64, 256, 0, stream>>>(dpw, cb);
      k_fft_x_pow<<<nbs * 64, 256, 0, stream>>>(cb, kbin, psd);

      k_cellin<<<CB, 256, 0, stream>>>(pos, dpw, Win_f, bin_f, bufC);
      k_clstm<<<nbs * 2048, 256, 0, stream>>>(bufC, bufN, c3, Wf, b3_f);
      k_wout<<<CB, 256, 0, stream>>>(bufN, Wo_f, bo_f, dpw);

      k_small<<<nbs, 256, 0, stream>>>(psp, psd, cnts, Wd1_f, bd1_f, Wlx_f, Wlh_f, bl_f,
                                       Wd2_f, bd2_f, Wc1_f, bc1_f, h1, c1, psn);

      k_fft_zy<<<nbs * 64, 256, 0, stream>>>(dpw, cb);
      k_fft_x_filt<<<nbs * 64, 256, 0, stream>>>(cb, kbin, psn);
      k_fft_zy_inv<<<nbs * 64, 256, 0, stream>>>(cb, pos, xtf, lsum);

      u16* tmp = bufC; bufC = bufN; bufN = tmp;
    }
    k_out<<<CB, 256, 0, stream>>>(pos, d_out, (size_t)b0 * VOL, flag);
  }
  k_loss<<<1, 1, 0, stream>>>(lsum, d_out, flag);
}

// Round 5
// 1704.434 us; speedup vs baseline: 3.5422x; 2.3167x over previous
//
#include <hip/hip_runtime.h>
#include <math.h>

#define NCC 64
#define NB 8
#define VOL (NCC*NCC*NCC)      // 262144 = 2^18
#define TOT (NB*VOL)           // 2097152
#define WTOT 170869            // total weight elements
#define PI2 6.2831853071795864769f

typedef unsigned short u16;
typedef __bf16 bf16x8 __attribute__((ext_vector_type(8)));
typedef float f32x16 __attribute__((ext_vector_type(16)));

__device__ __forceinline__ float b2f(u16 h){ return __uint_as_float(((unsigned)h)<<16); }
__device__ __forceinline__ u16 f2b(float f){
  unsigned u = __float_as_uint(f);
  unsigned r = (u + 0x7FFFu + ((u>>16)&1u)) >> 16;
  return (u16)r;
}
__device__ __forceinline__ float fsig(float x){ return 1.f / (1.f + __expf(-x)); }
__device__ __forceinline__ float ftanh(float x){
  float e = __expf(2.f * x);
  return 1.f - 2.f / (e + 1.f);
}

// ================= radix-8 FFT machinery =================
// fft8: DIF, output x[j] = X[bitrev3(j)], bitrev3 = {0,4,2,6,1,5,3,7}
template<bool INV>
__device__ __forceinline__ void fft8(float2* x) {
  const float C = 0.70710678118654752440f;
  float2 s0,s1,s2,s3,s4,s5,s6,s7;
  s0 = make_float2(x[0].x + x[4].x, x[0].y + x[4].y);
  s4 = make_float2(x[0].x - x[4].x, x[0].y - x[4].y);
  s1 = make_float2(x[1].x + x[5].x, x[1].y + x[5].y);
  s5 = make_float2(x[1].x - x[5].x, x[1].y - x[5].y);
  s2 = make_float2(x[2].x + x[6].x, x[2].y + x[6].y);
  s6 = make_float2(x[2].x - x[6].x, x[2].y - x[6].y);
  s3 = make_float2(x[3].x + x[7].x, x[3].y + x[7].y);
  s7 = make_float2(x[3].x - x[7].x, x[3].y - x[7].y);
  float2 n5, n6, n7;
  if (!INV) {
    n5 = make_float2(C*(s5.x + s5.y), C*(s5.y - s5.x));
    n6 = make_float2(s6.y, -s6.x);
    n7 = make_float2(C*(s7.y - s7.x), -C*(s7.x + s7.y));
  } else {
    n5 = make_float2(C*(s5.x - s5.y), C*(s5.y + s5.x));
    n6 = make_float2(-s6.y, s6.x);
    n7 = make_float2(-C*(s7.x + s7.y), C*(s7.x - s7.y));
  }
  float2 t0,t1,t2,t3,t4,t5,t6,t7,d;
  t0 = make_float2(s0.x + s2.x, s0.y + s2.y);
  t2 = make_float2(s0.x - s2.x, s0.y - s2.y);
  t1 = make_float2(s1.x + s3.x, s1.y + s3.y);
  d  = make_float2(s1.x - s3.x, s1.y - s3.y);
  t3 = INV ? make_float2(-d.y, d.x) : make_float2(d.y, -d.x);
  t4 = make_float2(s4.x + n6.x, s4.y + n6.y);
  t6 = make_float2(s4.x - n6.x, s4.y - n6.y);
  t5 = make_float2(n5.x + n7.x, n5.y + n7.y);
  d  = make_float2(n5.x - n7.x, n5.y - n7.y);
  t7 = INV ? make_float2(-d.y, d.x) : make_float2(d.y, -d.x);
  x[0] = make_float2(t0.x + t1.x, t0.y + t1.y);
  x[1] = make_float2(t0.x - t1.x, t0.y - t1.y);
  x[2] = make_float2(t2.x + t3.x, t2.y + t3.y);
  x[3] = make_float2(t2.x - t3.x, t2.y - t3.y);
  x[4] = make_float2(t4.x + t5.x, t4.y + t5.y);
  x[5] = make_float2(t4.x - t5.x, t4.y - t5.y);
  x[6] = make_float2(t6.x + t7.x, t6.y + t7.y);
  x[7] = make_float2(t6.x - t7.x, t6.y - t7.y);
}

// in-place 64-line x 64-pt DFT on padded plane; slot(L,n) = L*ls + n*ns.
// caller must __syncthreads() after filling P; ends synced.
template<bool INV>
__device__ __forceinline__ void dft64(float2* Pf, const float2* tw, int ls, int ns) {
  const int BR[8] = {0,4,2,6,1,5,3,7};
  int t = threadIdx.x;
  int L0 = t >> 3, b = t & 7, L1 = L0 + 32;
  float2 v0[8], v1[8];
  #pragma unroll
  for (int a = 0; a < 8; ++a) v0[a] = Pf[L0*ls + (8*a + b)*ns];
  #pragma unroll
  for (int a = 0; a < 8; ++a) v1[a] = Pf[L1*ls + (8*a + b)*ns];
  __syncthreads();
  fft8<INV>(v0); fft8<INV>(v1);
  #pragma unroll
  for (int r = 0; r < 8; ++r) {
    float2 w = tw[(b * r) & 63];
    if (INV) w.y = -w.y;
    float2 a0 = v0[BR[r]], a1 = v1[BR[r]];
    Pf[L0*ls + (8*b + r)*ns] = make_float2(a0.x*w.x - a0.y*w.y, a0.x*w.y + a0.y*w.x);
    Pf[L1*ls + (8*b + r)*ns] = make_float2(a1.x*w.x - a1.y*w.y, a1.x*w.y + a1.y*w.x);
  }
  __syncthreads();
  int r = t & 7;
  #pragma unroll
  for (int q = 0; q < 8; ++q) v0[q] = Pf[L0*ls + (8*q + r)*ns];
  #pragma unroll
  for (int q = 0; q < 8; ++q) v1[q] = Pf[L1*ls + (8*q + r)*ns];
  fft8<INV>(v0); fft8<INV>(v1);
  #pragma unroll
  for (int j = 0; j < 8; ++j) {
    Pf[L0*ls + (8*BR[j] + r)*ns] = v0[j];
    Pf[L1*ls + (8*BR[j] + r)*ns] = v1[j];
  }
  __syncthreads();
}

// ================= setup / small kernels =================
__global__ __launch_bounds__(256) void k_sniff(const u16* __restrict__ x, int* __restrict__ flag) {
  __shared__ int cnt;
  if (threadIdx.x == 0) cnt = 0;
  __syncthreads();
  int sane = 0;
  for (int i = threadIdx.x; i < 1024; i += 256) {
    u16 h = x[2 * i];
    int e = (h >> 7) & 0xFF;
    if (h == 0 || (e >= 0x68 && e <= 0x8F)) sane++;
  }
  atomicAdd(&cnt, sane);
  __syncthreads();
  if (threadIdx.x == 0) flag[0] = (cnt >= 768) ? 1 : 0;
}

__global__ __launch_bounds__(256) void k_cvt(const void* __restrict__ in, size_t eoff,
                                             float* __restrict__ out, const int* __restrict__ flag) {
  size_t i = (size_t)blockIdx.x * 256 + threadIdx.x;
  if (*flag) out[i] = b2f(((const u16*)in)[eoff + i]);
  else       out[i] = ((const float*)in)[eoff + i];
}

__global__ __launch_bounds__(256) void k_cvtall(
    const void* s0, const void* s1, const void* s2, const void* s3,
    const void* s4, const void* s5, const void* s6, const void* s7,
    const void* s8, const void* s9, const void* s10, const void* s11,
    const void* s12, const void* s13, const void* s14, const void* s15,
    float* __restrict__ out, const int* __restrict__ flag) {
  const void* ps[16] = {s0,s1,s2,s3,s4,s5,s6,s7,s8,s9,s10,s11,s12,s13,s14,s15};
  const int offs[17] = {0,432,440,7352,14264,14296,14512,14513,30897,31025,
                        96561,162097,162609,170801,170865,170868,170869};
  int i = blockIdx.x * 256 + threadIdx.x;
  if (i >= WTOT) return;
  int s = 0;
  #pragma unroll
  for (int k = 1; k < 16; ++k) if (i >= offs[k]) s = k;
  int j = i - offs[s];
  if (*flag) out[i] = b2f(((const u16*)ps[s])[j]);
  else       out[i] = ((const float*)ps[s])[j];
}

__global__ __launch_bounds__(256) void k_mkwf(const void* __restrict__ Wx, const void* __restrict__ Wh,
                                              const int* __restrict__ flag, u16* __restrict__ Wf) {
  int i = blockIdx.x * 256 + threadIdx.x;   // 13824
  if (i >= 13824) return;
  int k = i & 15, co = (i >> 4) & 31, tap = i >> 9;
  int src = tap * 256 + (k & 7) * 32 + co;
  const void* P = (k < 8) ? Wx : Wh;
  u16 val;
  if (*flag) val = ((const u16*)P)[src];
  else       val = f2b(((const float*)P)[src]);
  Wf[i] = val;
}

__global__ __launch_bounds__(256) void k_counts(const int* __restrict__ kbin,
                                                float* __restrict__ cnts) {
  __shared__ float s[NCC];
  int t = threadIdx.x;
  if (t < NCC) s[t] = 0.f;
  __syncthreads();
  int i = blockIdx.x * 256 + t;
  atomicAdd(&s[kbin[i]], 1.f);
  __syncthreads();
  if (t < NCC) atomicAdd(&cnts[t], s[t]);
}

__global__ __launch_bounds__(256) void k_adam(const float* __restrict__ pos,
                                              const float* __restrict__ y,
                                              float* __restrict__ m, float* __restrict__ v,
                                              float* __restrict__ delta,
                                              float ib1, float ib2, int first) {
  int i = blockIdx.x * 256 + threadIdx.x;
  float g  = pos[i] - y[i];
  float mi, vi;
  if (first) { mi = 0.1f * g; vi = 0.001f * g * g; }
  else { mi = 0.9f * m[i] + 0.1f * g; vi = 0.999f * v[i] + 0.001f * g * g; }
  m[i] = mi; v[i] = vi;
  delta[i] = -0.1f * (mi * ib1) / (sqrtf(vi * ib2) + 1e-7f);
}

// ================= FFT kernels (radix-8 planes) =================
__global__ __launch_bounds__(256) void k_fft_zy(const float* __restrict__ rin,
                                                float2* __restrict__ cout) {
  __shared__ float2 P[64*66];
  __shared__ float2 tw[64];
  int t = threadIdx.x;
  if (t < 64) { float s, c; __sincosf(-(PI2/64.f)*(float)t, &s, &c); tw[t] = make_float2(c, s); }
  const float* src = rin + (size_t)blockIdx.x * 4096;
  #pragma unroll
  for (int i = 0; i < 4; ++i) {
    float4 v = ((const float4*)src)[t + 256*i];
    int base = (t + 256*i) * 4;
    float2* row = P + (base >> 6)*66 + (base & 63);
    row[0] = make_float2(v.x, 0.f);
    row[1] = make_float2(v.y, 0.f);
    row[2] = make_float2(v.z, 0.f);
    row[3] = make_float2(v.w, 0.f);
  }
  __syncthreads();
  dft64<false>(P, tw, 66, 1);   // over z (lines = rows y)
  dft64<false>(P, tw, 1, 66);   // over y (lines = cols z)
  float4* dst = (float4*)(cout + (size_t)blockIdx.x * 4096);
  #pragma unroll
  for (int i = 0; i < 8; ++i) {
    int idx2 = (t + 256*i) * 2;
    float2 a = P[(idx2 >> 6)*66 + (idx2 & 63)];
    float2 b = P[(idx2 >> 6)*66 + (idx2 & 63) + 1];
    dst[t + 256*i] = make_float4(a.x, a.y, b.x, b.y);
  }
}

__global__ __launch_bounds__(256) void k_fft_x_pow(const float2* __restrict__ cin,
                                                   const int* __restrict__ kb,
                                                   float* __restrict__ psum) {
  __shared__ float2 P[64*66];
  __shared__ float2 tw[64];
  __shared__ float pb[64];
  int t = threadIdx.x;
  if (t < 64) { float s, c; __sincosf(-(PI2/64.f)*(float)t, &s, &c); tw[t] = make_float2(c, s); pb[t] = 0.f; }
  int b = blockIdx.x >> 6, y = blockIdx.x & 63;
  #pragma unroll
  for (int i = 0; i < 8; ++i) {
    int idx2 = (t + 256*i) * 2;
    int x = idx2 >> 6, z = idx2 & 63;
    float4 v = *(const float4*)(cin + (((size_t)(b*64 + x)*64 + y)*64 + z));
    P[x*66 + z]     = make_float2(v.x, v.y);
    P[x*66 + z + 1] = make_float2(v.z, v.w);
  }
  __syncthreads();
  dft64<false>(P, tw, 1, 66);   // over x (lines = cols z... L = z, n = x)
  const float INV2 = 1.0f / ((float)VOL * (float)VOL);
  #pragma unroll
  for (int i = 0; i < 16; ++i) {
    int idx = t + 256*i;
    int x = idx >> 6, z = idx & 63;
    float2 a = P[x*66 + z];
    float pm = (a.x*a.x + a.y*a.y) * INV2;
    atomicAdd(&pb[kb[(x*64 + y)*64 + z]], pm);
  }
  __syncthreads();
  if (t < 64) atomicAdd(&psum[b*64 + t], pb[t]);
}

__global__ __launch_bounds__(256) void k_fft_x_filt(float2* __restrict__ cb,
                                                    const int* __restrict__ kb,
                                                    const float* __restrict__ psn) {
  __shared__ float2 P[64*66];
  __shared__ float2 tw[64];
  int t = threadIdx.x;
  if (t < 64) { float s, c; __sincosf(-(PI2/64.f)*(float)t, &s, &c); tw[t] = make_float2(c, s); }
  int b = blockIdx.x >> 6, y = blockIdx.x & 63;
  #pragma unroll
  for (int i = 0; i < 8; ++i) {
    int idx2 = (t + 256*i) * 2;
    int x = idx2 >> 6, z = idx2 & 63;
    float4 v = *(const float4*)(cb + (((size_t)(b*64 + x)*64 + y)*64 + z));
    P[x*66 + z]     = make_float2(v.x, v.y);
    P[x*66 + z + 1] = make_float2(v.z, v.w);
  }
  __syncthreads();
  dft64<false>(P, tw, 1, 66);
  #pragma unroll
  for (int i = 0; i < 16; ++i) {
    int idx = t + 256*i;
    int x = idx >> 6, z = idx & 63;
    float fac = sqrtf(psn[b*64 + kb[(x*64 + y)*64 + z]]);
    float2 a = P[x*66 + z];
    P[x*66 + z] = make_float2(a.x * fac, a.y * fac);
  }
  __syncthreads();
  dft64<true>(P, tw, 1, 66);
  #pragma unroll
  for (int i = 0; i < 8; ++i) {
    int idx2 = (t + 256*i) * 2;
    int x = idx2 >> 6, z = idx2 & 63;
    float2 a = P[x*66 + z], c = P[x*66 + z + 1];
    *(float4*)(cb + (((size_t)(b*64 + x)*64 + y)*64 + z)) = make_float4(a.x, a.y, c.x, c.y);
  }
}

__global__ __launch_bounds__(256) void k_fft_zy_inv(const float2* __restrict__ cin,
                                                    float* __restrict__ pos,
                                                    const float* __restrict__ xtf,
                                                    float* __restrict__ lsum) {
  __shared__ float2 P[64*66];
  __shared__ float2 tw[64];
  __shared__ float red[256];
  int t = threadIdx.x;
  if (t < 64) { float s, c; __sincosf(-(PI2/64.f)*(float)t, &s, &c); tw[t] = make_float2(c, s); }
  const float4* src = (const float4*)(cin + (size_t)blockIdx.x * 4096);
  #pragma unroll
  for (int i = 0; i < 8; ++i) {
    float4 v = src[t + 256*i];
    int idx2 = (t + 256*i) * 2;
    P[(idx2 >> 6)*66 + (idx2 & 63)]     = make_float2(v.x, v.y);
    P[(idx2 >> 6)*66 + (idx2 & 63) + 1] = make_float2(v.z, v.w);
  }
  __syncthreads();
  dft64<true>(P, tw, 1, 66);    // inverse over y
  dft64<true>(P, tw, 66, 1);    // inverse over z
  float* pdst = pos + (size_t)blockIdx.x * 4096;
  const float* xt = xtf + (size_t)blockIdx.x * 4096;
  float lacc = 0.f;
  #pragma unroll
  for (int i = 0; i < 16; ++i) {
    int idx = t + 256*i;
    float np = pdst[idx] + P[(idx >> 6)*66 + (idx & 63)].x * (1.0f/(float)VOL);
    pdst[idx] = np;
    float d = xt[idx] - np;
    lacc = fmaf(d, d, lacc);
  }
  red[t] = lacc; __syncthreads();
  for (int s = 128; s > 0; s >>= 1) { if (t < s) red[t] += red[t+s]; __syncthreads(); }
  if (t == 0) atomicAdd(lsum, red[0]);
}

// ================= conv path =================
__global__ __launch_bounds__(256) void k_cellin(const float* __restrict__ pos,
                                                const float* __restrict__ delta,
                                                const float* __restrict__ Win,
                                                const float* __restrict__ binf,
                                                u16* __restrict__ ci) {
  int id = blockIdx.x * 256 + threadIdx.x;
  int z = id & 63, yy = (id >> 6) & 63, x = (id >> 12) & 63, b = id >> 18;
  float acc[8];
  #pragma unroll
  for (int c = 0; c < 8; ++c) acc[c] = binf[c];
  #pragma unroll 1
  for (int tap = 0; tap < 27; ++tap) {
    int kd = tap / 9, kh = (tap / 3) % 3, kw = tap % 3;
    int nx = x + kd - 1, ny = yy + kh - 1, nz = z + kw - 1;
    if ((unsigned)nx >= 64u || (unsigned)ny >= 64u || (unsigned)nz >= 64u) continue;
    size_t n = (((size_t)b * 64 + nx) * 64 + ny) * 64 + nz;
    float p = pos[n], d = delta[n];
    const float* w = Win + tap * 16;
    #pragma unroll
    for (int c = 0; c < 8; ++c) acc[c] = fmaf(p, w[c], fmaf(d, w[8 + c], acc[c]));
  }
  u16 hh[8];
  #pragma unroll
  for (int c = 0; c < 8; ++c) hh[c] = f2b(acc[c]);
  *(uint4*)(ci + (size_t)id * 8) = *(uint4*)hh;
}

__global__ __launch_bounds__(256) void k_clstm(const u16* __restrict__ ci,
                                               const u16* __restrict__ hC,
                                               u16* __restrict__ hN,
                                               u16* __restrict__ c3u,
                                               const u16* __restrict__ Wf,
                                               const float* __restrict__ b3f) {
  __shared__ float zl[4][32][33];
  int t = threadIdx.x;
  int wv = t >> 6, l = t & 63, ln = l & 31, hi = l >> 5;
  int bid = blockIdx.x;
  int ypair = bid & 31, x = (bid >> 5) & 63, b = bid >> 11;
  int y = ypair * 2 + (wv >> 1);
  int z0 = (wv & 1) * 32;
  bf16x8 Bfr[27];
  #pragma unroll
  for (int tap = 0; tap < 27; ++tap) {
    uint4 w = *(const uint4*)(Wf + ((tap * 32 + ln) * 16 + hi * 8));
    Bfr[tap] = __builtin_bit_cast(bf16x8, w);
  }
  f32x16 acc;
  #pragma unroll
  for (int r = 0; r < 16; ++r) acc[r] = 0.f;
  int z = z0 + ln;
  const u16* abase = hi ? hC : ci;
  #pragma unroll
  for (int tap = 0; tap < 27; ++tap) {
    int dx = tap / 9 - 1, dy = (tap / 3) % 3 - 1, dz = tap % 3 - 1;
    int nx = x + dx, ny = y + dy, nz = z + dz;
    bf16x8 afr = __builtin_bit_cast(bf16x8, make_uint4(0, 0, 0, 0));
    if ((unsigned)nx < 64u && (unsigned)ny < 64u && (unsigned)nz < 64u) {
      size_t vox = (((size_t)b * 64 + nx) * 64 + ny) * 64 + nz;
      uint4 a = *(const uint4*)(abase + vox * 8);
      afr = __builtin_bit_cast(bf16x8, a);
    }
    acc = __builtin_amdgcn_mfma_f32_32x32x16_bf16(afr, Bfr[tap], acc, 0, 0, 0);
  }
  float bz = b3f[ln];
  #pragma unroll
  for (int r = 0; r < 16; ++r) {
    int row = (r & 3) + 8 * (r >> 2) + 4 * hi;
    zl[wv][row][ln] = acc[r] + bz;
  }
  __syncthreads();
  int m = ln;
  size_t vox = (((size_t)b * 64 + x) * 64 + y) * 64 + z0 + m;
  uint2 cu = *(const uint2*)(c3u + vox * 8 + hi * 4);
  const u16* cp = (const u16*)&cu;
  u16 cw[4], hw[4];
  #pragma unroll
  for (int q = 0; q < 4; ++q) {
    int cc = hi * 4 + q;
    float zi  = zl[wv][m][cc];
    float zf  = zl[wv][m][cc + 8];
    float zg  = zl[wv][m][cc + 16];
    float zo_ = zl[wv][m][cc + 24];
    float cn = fsig(zf) * b2f(cp[q]) + fsig(zi) * ftanh(zg);
    cw[q] = f2b(cn);
    hw[q] = f2b(fsig(zo_) * ftanh(cn));
  }
  *(uint2*)(c3u + vox * 8 + hi * 4) = *(uint2*)cw;
  *(uint2*)(hN + vox * 8 + hi * 4)  = *(uint2*)hw;
}

__global__ __launch_bounds__(256) void k_wout(const u16* __restrict__ h,
                                              const float* __restrict__ Wo,
                                              const float* __restrict__ bo,
                                              float* __restrict__ dpw) {
  int id = blockIdx.x * 256 + threadIdx.x;
  int z = id & 63, yy = (id >> 6) & 63, x = (id >> 12) & 63, b = id >> 18;
  float acc = bo[0];
  #pragma unroll 1
  for (int tap = 0; tap < 27; ++tap) {
    int kd = tap / 9, kh = (tap / 3) % 3, kw = tap % 3;
    int nx = x + kd - 1, ny = yy + kh - 1, nz = z + kw - 1;
    if ((unsigned)nx >= 64u || (unsigned)ny >= 64u || (unsigned)nz >= 64u) continue;
    size_t n = (((size_t)b * 64 + nx) * 64 + ny) * 64 + nz;
    uint4 a = *(const uint4*)(h + n * 8);
    const u16* hp = (const u16*)&a;
    const float* w = Wo + tap * 8;
    #pragma unroll
    for (int c = 0; c < 8; ++c) acc = fmaf(b2f(hp[c]), w[c], acc);
  }
  dpw[id] = acc;
}

// ================= small dense LSTM branch =================
__global__ __launch_bounds__(256) void k_small(const float* __restrict__ psp,
                                               const float* __restrict__ psd,
                                               const float* __restrict__ cnts,
                                               const float* __restrict__ Wd1,
                                               const float* __restrict__ bd1,
                                               const float* __restrict__ Wlx,
                                               const float* __restrict__ Wlh,
                                               const float* __restrict__ bl,
                                               const float* __restrict__ Wd2,
                                               const float* __restrict__ bd2,
                                               const float* __restrict__ Wc1,
                                               const float* __restrict__ bc1,
                                               float* __restrict__ h1, float* __restrict__ c1,
                                               float* __restrict__ psn) {
  __shared__ float lp[128], x1[128], hs[128], zz[512], lps[66];
  int t = threadIdx.x, b = blockIdx.x;
  if (t < 64) {
    lp[t]      = __log10f(fmaxf(psp[b*64 + t] / cnts[t] * 8.0e6f, 1e-30f));
    lp[64 + t] = __log10f(fmaxf(psd[b*64 + t] / cnts[t] * 8.0e6f, 1e-30f));
  }
  if (t < 128) hs[t] = h1[b*128 + t];
  __syncthreads();
  if (t < 128) {
    float a = bd1[t];
    for (int j = 0; j < 128; ++j) a = fmaf(lp[j], Wd1[j*128 + t], a);
    x1[t] = a;
  }
  __syncthreads();
  for (int k = t; k < 512; k += 256) {
    float a = bl[k];
    for (int u = 0; u < 128; ++u)
      a = fmaf(x1[u], Wlx[u*512 + k], fmaf(hs[u], Wlh[u*512 + k], a));
    zz[k] = a;
  }
  __syncthreads();
  if (t < 128) {
    float cv = fsig(zz[128 + t]) * c1[b*128 + t] + fsig(zz[t]) * ftanh(zz[256 + t]);
    c1[b*128 + t] = cv;
    float hv = fsig(zz[384 + t]) * ftanh(cv);
    h1[b*128 + t] = hv; hs[t] = hv;
  }
  __syncthreads();
  if (t < 64) {
    float a = bd2[t];
    for (int u = 0; u < 128; ++u) a = fmaf(hs[u], Wd2[u*64 + t], a);
    lps[t + 1] = a;
  }
  __syncthreads();
  if (t < 64) {
    float a = fmaf(Wc1[1], lps[t + 1], bc1[0]);
    if (t > 0)  a = fmaf(Wc1[0], lps[t], a);
    if (t < 63) a = fmaf(Wc1[2], lps[t + 2], a);
    psn[b*64 + t] = __expf(a);
  }
}

// ================= output =================
__global__ __launch_bounds__(256) void k_out(const float* __restrict__ pos, void* __restrict__ outp,
                                             size_t eoff, const int* __restrict__ flag) {
  size_t i = (size_t)blockIdx.x * 256 + threadIdx.x;
  if (*flag) ((u16*)outp)[eoff + i] = f2b(pos[i]);
  else       ((float*)outp)[eoff + i] = pos[i];
}

__global__ void k_loss(const float* __restrict__ lsum, void* __restrict__ outp,
                       const int* __restrict__ flag) {
  float l = lsum[0] * (1.0f / (float)TOT);
  if (*flag) ((u16*)outp)[TOT] = f2b(l);
  else       ((float*)outp)[TOT] = l;
}

__global__ void k_sent(u16* __restrict__ outp) { outp[0] = f2b(1000.0f); }

extern "C" void kernel_launch(void* const* d_in, const int* in_sizes, int n_in,
                              void* d_out, int out_size, void* d_ws, size_t ws_size,
                              hipStream_t stream) {
  const void* x_init = d_in[0];
  const void* y      = d_in[1];
  const void* x_true = d_in[2];
  const int*  kbin   = (const int*)d_in[3];

  int nbs = 0;
  for (int cand = 8; cand >= 1; cand >>= 1) {
    size_t n1c = (size_t)cand * VOL;
    size_t need = ((size_t)24 * n1c + 171008 + 6912 +
                   (size_t)cand * (192 + 256) + 64 + 8 + 64) * sizeof(float);
    if (need <= ws_size) { nbs = cand; break; }
  }
  if (nbs == 0) { k_sent<<<1, 1, 0, stream>>>((u16*)d_out); return; }

  size_t n1 = (size_t)nbs * VOL;
  float* ws   = (float*)d_ws;
  float* pos  = ws;
  float* m    = pos + n1;
  float* v    = m + n1;
  float* dpw  = v + n1;
  float* yf   = dpw + n1;
  float* xtf  = yf + n1;
  float2* cb  = (float2*)(xtf + n1);          // 2n1 f32
  u16*  c3u   = (u16*)((float*)cb + n1*2);    // 8n1 u16
  u16*  ci    = c3u + n1*8;                   // 8n1 u16
  u16*  hA    = ci + n1*8;                    // 8n1 u16
  u16*  hB    = hA + n1*8;                    // 8n1 u16
  float* wbuf = (float*)(hB + n1*8);          // 171008 f32
  u16*  Wf    = (u16*)(wbuf + 171008);        // 13824 u16
  float* psp  = wbuf + 171008 + 6912;
  float* psd  = psp + (size_t)nbs*64;
  float* psn  = psd + (size_t)nbs*64;
  float* cnts = psn + (size_t)nbs*64;
  float* lsum = cnts + 64;                    // 8
  float* h1   = lsum + 8;
  float* c1   = h1 + (size_t)nbs*128;
  int*   flag = (int*)(c1 + (size_t)nbs*128);

  float* Win_f = wbuf + 0;     float* bin_f = wbuf + 432;
  float* b3_f  = wbuf + 14264; float* Wo_f  = wbuf + 14296;
  float* bo_f  = wbuf + 14512; float* Wd1_f = wbuf + 14513;
  float* bd1_f = wbuf + 30897; float* Wlx_f = wbuf + 31025;
  float* Wlh_f = wbuf + 96561; float* bl_f  = wbuf + 162097;
  float* Wd2_f = wbuf + 162609; float* bd2_f = wbuf + 170801;
  float* Wc1_f = wbuf + 170865; float* bc1_f = wbuf + 170868;

  const int CB = (int)(n1 / 256);

  k_sniff<<<1, 256, 0, stream>>>((const u16*)x_init, flag);
  k_cvtall<<<(WTOT + 255) / 256, 256, 0, stream>>>(
      d_in[4], d_in[5], d_in[6], d_in[7], d_in[8], d_in[9], d_in[10], d_in[11],
      d_in[12], d_in[13], d_in[14], d_in[15], d_in[16], d_in[17], d_in[18], d_in[19],
      wbuf, flag);
  k_mkwf<<<54, 256, 0, stream>>>(d_in[6], d_in[7], flag, Wf);
  hipMemsetAsync(cnts, 0, 64 * 4, stream);
  hipMemsetAsync(lsum, 0, 8 * 4, stream);
  k_counts<<<VOL / 256, 256, 0, stream>>>(kbin, cnts);

  for (int b0 = 0; b0 < NB; b0 += nbs) {
    hipMemsetAsync(c3u, 0, n1 * 16, stream);
    hipMemsetAsync(hA, 0, n1 * 16, stream);
    hipMemsetAsync(h1, 0, (size_t)nbs * 256 * 4, stream);
    k_cvt<<<CB, 256, 0, stream>>>(x_init, (size_t)b0 * VOL, pos, flag);
    k_cvt<<<CB, 256, 0, stream>>>(y,      (size_t)b0 * VOL, yf, flag);
    k_cvt<<<CB, 256, 0, stream>>>(x_true, (size_t)b0 * VOL, xtf, flag);

    u16* hC = hA;
    u16* hN = hB;
    for (int t = 1; t <= 4; ++t) {
      float ib1 = (float)(1.0 / (1.0 - pow(0.9, (double)t)));
      float ib2 = (float)(1.0 / (1.0 - pow(0.999, (double)t)));
      k_adam<<<CB, 256, 0, stream>>>(pos, yf, m, v, dpw, ib1, ib2, t == 1);

      hipMemsetAsync(psp, 0, (size_t)nbs * 64 * 4, stream);
      k_fft_zy<<<nbs * 64, 256, 0, stream>>>(pos, cb);
      k_fft_x_pow<<<nbs * 64, 256, 0, stream>>>(cb, kbin, psp);

      hipMemsetAsync(psd, 0, (size_t)nbs * 64 * 4, stream);
      k_fft_zy<<<nbs * 64, 256, 0, stream>>>(dpw, cb);
      k_fft_x_pow<<<nbs * 64, 256, 0, stream>>>(cb, kbin, psd);

      k_cellin<<<CB, 256, 0, stream>>>(pos, dpw, Win_f, bin_f, ci);
      k_clstm<<<nbs * 2048, 256, 0, stream>>>(ci, hC, hN, c3u, Wf, b3_f);
      k_wout<<<CB, 256, 0, stream>>>(hN, Wo_f, bo_f, dpw);

      k_small<<<nbs, 256, 0, stream>>>(psp, psd, cnts, Wd1_f, bd1_f, Wlx_f, Wlh_f, bl_f,
                                       Wd2_f, bd2_f, Wc1_f, bc1_f, h1, c1, psn);

      k_fft_zy<<<nbs * 64, 256, 0, stream>>>(dpw, cb);
      k_fft_x_filt<<<nbs * 64, 256, 0, stream>>>(cb, kbin, psn);
      k_fft_zy_inv<<<nbs * 64, 256, 0, stream>>>(cb, pos, xtf, lsum);

      u16* tmp = hC; hC = hN; hN = tmp;
    }
    k_out<<<CB, 256, 0, stream>>>(pos, d_out, (size_t)b0 * VOL, flag);
  }
  k_loss<<<1, 1, 0, stream>>>(lsum, d_out, flag);
}

// Round 7
// 1609.060 us; speedup vs baseline: 3.7522x; 1.0593x over previous
//
#include <hip/hip_runtime.h>
#include <math.h>

#define NCC 64
#define NB 8
#define VOL (NCC*NCC*NCC)      // 262144 = 2^18
#define TOT (NB*VOL)           // 2097152
#define WTOT 170869            // total weight elements
#define PI2 6.2831853071795864769f
#define SLOTS1 270336          // 64*64*66 halo slots per batch

typedef unsigned short u16;
typedef __bf16 bf16x8 __attribute__((ext_vector_type(8)));
typedef float f32x16 __attribute__((ext_vector_type(16)));

__device__ __forceinline__ float b2f(u16 h){ return __uint_as_float(((unsigned)h)<<16); }
__device__ __forceinline__ u16 f2b(float f){
  unsigned u = __float_as_uint(f);
  unsigned r = (u + 0x7FFFu + ((u>>16)&1u)) >> 16;
  return (u16)r;
}
__device__ __forceinline__ float fsig(float x){ return 1.f / (1.f + __expf(-x)); }
__device__ __forceinline__ float ftanh(float x){
  float e = __expf(2.f * x);
  return 1.f - 2.f / (e + 1.f);
}

// ================= radix-8 FFT machinery =================
template<bool INV>
__device__ __forceinline__ void fft8(float2* x) {
  const float C = 0.70710678118654752440f;
  float2 s0,s1,s2,s3,s4,s5,s6,s7;
  s0 = make_float2(x[0].x + x[4].x, x[0].y + x[4].y);
  s4 = make_float2(x[0].x - x[4].x, x[0].y - x[4].y);
  s1 = make_float2(x[1].x + x[5].x, x[1].y + x[5].y);
  s5 = make_float2(x[1].x - x[5].x, x[1].y - x[5].y);
  s2 = make_float2(x[2].x + x[6].x, x[2].y + x[6].y);
  s6 = make_float2(x[2].x - x[6].x, x[2].y - x[6].y);
  s3 = make_float2(x[3].x + x[7].x, x[3].y + x[7].y);
  s7 = make_float2(x[3].x - x[7].x, x[3].y - x[7].y);
  float2 n5, n6, n7;
  if (!INV) {
    n5 = make_float2(C*(s5.x + s5.y), C*(s5.y - s5.x));
    n6 = make_float2(s6.y, -s6.x);
    n7 = make_float2(C*(s7.y - s7.x), -C*(s7.x + s7.y));
  } else {
    n5 = make_float2(C*(s5.x - s5.y), C*(s5.y + s5.x));
    n6 = make_float2(-s6.y, s6.x);
    n7 = make_float2(-C*(s7.x + s7.y), C*(s7.x - s7.y));
  }
  float2 t0,t1,t2,t3,t4,t5,t6,t7,d;
  t0 = make_float2(s0.x + s2.x, s0.y + s2.y);
  t2 = make_float2(s0.x - s2.x, s0.y - s2.y);
  t1 = make_float2(s1.x + s3.x, s1.y + s3.y);
  d  = make_float2(s1.x - s3.x, s1.y - s3.y);
  t3 = INV ? make_float2(-d.y, d.x) : make_float2(d.y, -d.x);
  t4 = make_float2(s4.x + n6.x, s4.y + n6.y);
  t6 = make_float2(s4.x - n6.x, s4.y - n6.y);
  t5 = make_float2(n5.x + n7.x, n5.y + n7.y);
  d  = make_float2(n5.x - n7.x, n5.y - n7.y);
  t7 = INV ? make_float2(-d.y, d.x) : make_float2(d.y, -d.x);
  x[0] = make_float2(t0.x + t1.x, t0.y + t1.y);
  x[1] = make_float2(t0.x - t1.x, t0.y - t1.y);
  x[2] = make_float2(t2.x + t3.x, t2.y + t3.y);
  x[3] = make_float2(t2.x - t3.x, t2.y - t3.y);
  x[4] = make_float2(t4.x + t5.x, t4.y + t5.y);
  x[5] = make_float2(t4.x - t5.x, t4.y - t5.y);
  x[6] = make_float2(t6.x + t7.x, t6.y + t7.y);
  x[7] = make_float2(t6.x - t7.x, t6.y - t7.y);
}

template<bool INV>
__device__ __forceinline__ void dft64(float2* Pf, const float2* tw, int ls, int ns) {
  const int BR[8] = {0,4,2,6,1,5,3,7};
  int t = threadIdx.x;
  int L0 = t >> 3, b = t & 7, L1 = L0 + 32;
  float2 v0[8], v1[8];
  #pragma unroll
  for (int a = 0; a < 8; ++a) v0[a] = Pf[L0*ls + (8*a + b)*ns];
  #pragma unroll
  for (int a = 0; a < 8; ++a) v1[a] = Pf[L1*ls + (8*a + b)*ns];
  __syncthreads();
  fft8<INV>(v0); fft8<INV>(v1);
  #pragma unroll
  for (int r = 0; r < 8; ++r) {
    float2 w = tw[(b * r) & 63];
    if (INV) w.y = -w.y;
    float2 a0 = v0[BR[r]], a1 = v1[BR[r]];
    Pf[L0*ls + (8*b + r)*ns] = make_float2(a0.x*w.x - a0.y*w.y, a0.x*w.y + a0.y*w.x);
    Pf[L1*ls + (8*b + r)*ns] = make_float2(a1.x*w.x - a1.y*w.y, a1.x*w.y + a1.y*w.x);
  }
  __syncthreads();
  int r = t & 7;
  #pragma unroll
  for (int q = 0; q < 8; ++q) v0[q] = Pf[L0*ls + (8*q + r)*ns];
  #pragma unroll
  for (int q = 0; q < 8; ++q) v1[q] = Pf[L1*ls + (8*q + r)*ns];
  fft8<INV>(v0); fft8<INV>(v1);
  #pragma unroll
  for (int j = 0; j < 8; ++j) {
    Pf[L0*ls + (8*BR[j] + r)*ns] = v0[j];
    Pf[L1*ls + (8*BR[j] + r)*ns] = v1[j];
  }
  __syncthreads();
}

// ================= setup kernels =================
__global__ __launch_bounds__(256) void k_sniff(const u16* __restrict__ x, int* __restrict__ flag) {
  __shared__ int cnt;
  if (threadIdx.x == 0) cnt = 0;
  __syncthreads();
  int sane = 0;
  for (int i = threadIdx.x; i < 1024; i += 256) {
    u16 h = x[2 * i];
    int e = (h >> 7) & 0xFF;
    if (h == 0 || (e >= 0x68 && e <= 0x8F)) sane++;
  }
  atomicAdd(&cnt, sane);
  __syncthreads();
  if (threadIdx.x == 0) flag[0] = (cnt >= 768) ? 1 : 0;
}

__global__ __launch_bounds__(256) void k_cvt(const void* __restrict__ in, size_t eoff,
                                             float* __restrict__ out, const int* __restrict__ flag) {
  size_t i = (size_t)blockIdx.x * 256 + threadIdx.x;
  if (*flag) out[i] = b2f(((const u16*)in)[eoff + i]);
  else       out[i] = ((const float*)in)[eoff + i];
}

__global__ __launch_bounds__(256) void k_cvtall(
    const void* s0, const void* s1, const void* s2, const void* s3,
    const void* s4, const void* s5, const void* s6, const void* s7,
    const void* s8, const void* s9, const void* s10, const void* s11,
    const void* s12, const void* s13, const void* s14, const void* s15,
    float* __restrict__ out, const int* __restrict__ flag) {
  const void* ps[16] = {s0,s1,s2,s3,s4,s5,s6,s7,s8,s9,s10,s11,s12,s13,s14,s15};
  const int offs[17] = {0,432,440,7352,14264,14296,14512,14513,30897,31025,
                        96561,162097,162609,170801,170865,170868,170869};
  int i = blockIdx.x * 256 + threadIdx.x;
  if (i >= WTOT) return;
  int s = 0;
  #pragma unroll
  for (int k = 1; k < 16; ++k) if (i >= offs[k]) s = k;
  int j = i - offs[s];
  if (*flag) out[i] = b2f(((const u16*)ps[s])[j]);
  else       out[i] = ((const float*)ps[s])[j];
}

// Wf[tap][hi][co][j] : u16 idx = tap*512 + hi*256 + co*8 + j
__global__ __launch_bounds__(256) void k_mkwf(const void* __restrict__ Wx, const void* __restrict__ Wh,
                                              const int* __restrict__ flag, u16* __restrict__ Wf) {
  int i = blockIdx.x * 256 + threadIdx.x;   // 13824
  if (i >= 13824) return;
  int j = i & 7, co = (i >> 3) & 31, hi = (i >> 8) & 1, tap = i >> 9;
  int src = tap * 256 + j * 32 + co;
  const void* P = hi ? Wh : Wx;
  u16 val;
  if (*flag) val = ((const u16*)P)[src];
  else       val = f2b(((const float*)P)[src]);
  Wf[i] = val;
}

__global__ __launch_bounds__(256) void k_counts(const int* __restrict__ kbin,
                                                float* __restrict__ cnts) {
  __shared__ float s[NCC];
  int t = threadIdx.x;
  if (t < NCC) s[t] = 0.f;
  __syncthreads();
  int i = blockIdx.x * 256 + t;
  atomicAdd(&s[kbin[i]], 1.f);
  __syncthreads();
  if (t < NCC) atomicAdd(&cnts[t], s[t]);
}

// ================= FFT kernels =================
__global__ __launch_bounds__(256) void k_fft_zy_adam(
    const float* __restrict__ pos, const void* __restrict__ yraw, size_t yoff,
    float* __restrict__ m, float* __restrict__ v, float* __restrict__ dpw,
    float2* __restrict__ cout, float ib1, float ib2, int first,
    const int* __restrict__ flag) {
  __shared__ float2 P[64*66];
  __shared__ float2 tw[64];
  int t = threadIdx.x;
  if (t < 64) { float s, c; __sincosf(-(PI2/64.f)*(float)t, &s, &c); tw[t] = make_float2(c, s); }
  size_t pb = (size_t)blockIdx.x * 4096;
  int bf = *flag;
  #pragma unroll
  for (int i = 0; i < 4; ++i) {
    int i4 = t + 256*i;
    float4 p4 = ((const float4*)(pos + pb))[i4];
    float yv[4];
    if (bf) {
      uint2 yu = ((const uint2*)((const u16*)yraw + yoff + pb))[i4];
      const u16* yp = (const u16*)&yu;
      yv[0]=b2f(yp[0]); yv[1]=b2f(yp[1]); yv[2]=b2f(yp[2]); yv[3]=b2f(yp[3]);
    } else {
      float4 y4 = ((const float4*)((const float*)yraw + yoff + pb))[i4];
      yv[0]=y4.x; yv[1]=y4.y; yv[2]=y4.z; yv[3]=y4.w;
    }
    float pv[4] = {p4.x, p4.y, p4.z, p4.w};
    float mo[4], vo[4], dd[4];
    if (!first) {
      float4 m4 = ((const float4*)(m + pb))[i4];
      float4 v4 = ((const float4*)(v + pb))[i4];
      mo[0]=m4.x; mo[1]=m4.y; mo[2]=m4.z; mo[3]=m4.w;
      vo[0]=v4.x; vo[1]=v4.y; vo[2]=v4.z; vo[3]=v4.w;
    }
    #pragma unroll
    for (int c = 0; c < 4; ++c) {
      float g = pv[c] - yv[c];
      float mi = first ? 0.1f*g : 0.9f*mo[c] + 0.1f*g;
      float vi = first ? 0.001f*g*g : 0.999f*vo[c] + 0.001f*g*g;
      mo[c] = mi; vo[c] = vi;
      dd[c] = -0.1f * (mi * ib1) / (sqrtf(vi * ib2) + 1e-7f);
    }
    ((float4*)(m + pb))[i4]   = make_float4(mo[0], mo[1], mo[2], mo[3]);
    ((float4*)(v + pb))[i4]   = make_float4(vo[0], vo[1], vo[2], vo[3]);
    ((float4*)(dpw + pb))[i4] = make_float4(dd[0], dd[1], dd[2], dd[3]);
    int base = i4 * 4;
    float2* row = P + (base >> 6)*66 + (base & 63);
    row[0] = make_float2(pv[0], 0.f);
    row[1] = make_float2(pv[1], 0.f);
    row[2] = make_float2(pv[2], 0.f);
    row[3] = make_float2(pv[3], 0.f);
  }
  __syncthreads();
  dft64<false>(P, tw, 66, 1);
  dft64<false>(P, tw, 1, 66);
  float4* dst = (float4*)(cout + pb);
  #pragma unroll
  for (int i = 0; i < 8; ++i) {
    int idx2 = (t + 256*i) * 2;
    float2 a = P[(idx2 >> 6)*66 + (idx2 & 63)];
    float2 b = P[(idx2 >> 6)*66 + (idx2 & 63) + 1];
    dst[t + 256*i] = make_float4(a.x, a.y, b.x, b.y);
  }
}

__global__ __launch_bounds__(256) void k_fft_zy(const float* __restrict__ rin,
                                                float2* __restrict__ cout) {
  __shared__ float2 P[64*66];
  __shared__ float2 tw[64];
  int t = threadIdx.x;
  if (t < 64) { float s, c; __sincosf(-(PI2/64.f)*(float)t, &s, &c); tw[t] = make_float2(c, s); }
  const float* src = rin + (size_t)blockIdx.x * 4096;
  #pragma unroll
  for (int i = 0; i < 4; ++i) {
    float4 v = ((const float4*)src)[t + 256*i];
    int base = (t + 256*i) * 4;
    float2* row = P + (base >> 6)*66 + (base & 63);
    row[0] = make_float2(v.x, 0.f);
    row[1] = make_float2(v.y, 0.f);
    row[2] = make_float2(v.z, 0.f);
    row[3] = make_float2(v.w, 0.f);
  }
  __syncthreads();
  dft64<false>(P, tw, 66, 1);
  dft64<false>(P, tw, 1, 66);
  float4* dst = (float4*)(cout + (size_t)blockIdx.x * 4096);
  #pragma unroll
  for (int i = 0; i < 8; ++i) {
    int idx2 = (t + 256*i) * 2;
    float2 a = P[(idx2 >> 6)*66 + (idx2 & 63)];
    float2 b = P[(idx2 >> 6)*66 + (idx2 & 63) + 1];
    dst[t + 256*i] = make_float4(a.x, a.y, b.x, b.y);
  }
}

__global__ __launch_bounds__(256) void k_fft_x_pow(const float2* __restrict__ cin,
                                                   const int* __restrict__ kb,
                                                   float* __restrict__ psum) {
  __shared__ float2 P[64*66];
  __shared__ float2 tw[64];
  __shared__ float pb[64];
  int t = threadIdx.x;
  if (t < 64) { float s, c; __sincosf(-(PI2/64.f)*(float)t, &s, &c); tw[t] = make_float2(c, s); pb[t] = 0.f; }
  int b = blockIdx.x >> 6, y = blockIdx.x & 63;
  #pragma unroll
  for (int i = 0; i < 8; ++i) {
    int idx2 = (t + 256*i) * 2;
    int x = idx2 >> 6, z = idx2 & 63;
    float4 v = *(const float4*)(cin + (((size_t)(b*64 + x)*64 + y)*64 + z));
    P[x*66 + z]     = make_float2(v.x, v.y);
    P[x*66 + z + 1] = make_float2(v.z, v.w);
  }
  __syncthreads();
  dft64<false>(P, tw, 1, 66);
  const float INV2 = 1.0f / ((float)VOL * (float)VOL);
  #pragma unroll
  for (int i = 0; i < 16; ++i) {
    int idx = t + 256*i;
    int x = idx >> 6, z = idx & 63;
    float2 a = P[x*66 + z];
    float pm = (a.x*a.x + a.y*a.y) * INV2;
    atomicAdd(&pb[kb[(x*64 + y)*64 + z]], pm);
  }
  __syncthreads();
  if (t < 64) atomicAdd(&psum[b*64 + t], pb[t]);
}

__global__ __launch_bounds__(256) void k_fft_x_filt(float2* __restrict__ cb,
                                                    const int* __restrict__ kb,
                                                    const float* __restrict__ psn) {
  __shared__ float2 P[64*66];
  __shared__ float2 tw[64];
  int t = threadIdx.x;
  if (t < 64) { float s, c; __sincosf(-(PI2/64.f)*(float)t, &s, &c); tw[t] = make_float2(c, s); }
  int b = blockIdx.x >> 6, y = blockIdx.x & 63;
  #pragma unroll
  for (int i = 0; i < 8; ++i) {
    int idx2 = (t + 256*i) * 2;
    int x = idx2 >> 6, z = idx2 & 63;
    float4 v = *(const float4*)(cb + (((size_t)(b*64 + x)*64 + y)*64 + z));
    P[x*66 + z]     = make_float2(v.x, v.y);
    P[x*66 + z + 1] = make_float2(v.z, v.w);
  }
  __syncthreads();
  dft64<false>(P, tw, 1, 66);
  #pragma unroll
  for (int i = 0; i < 16; ++i) {
    int idx = t + 256*i;
    int x = idx >> 6, z = idx & 63;
    float fac = sqrtf(psn[b*64 + kb[(x*64 + y)*64 + z]]);
    float2 a = P[x*66 + z];
    P[x*66 + z] = make_float2(a.x * fac, a.y * fac);
  }
  __syncthreads();
  dft64<true>(P, tw, 1, 66);
  #pragma unroll
  for (int i = 0; i < 8; ++i) {
    int idx2 = (t + 256*i) * 2;
    int x = idx2 >> 6, z = idx2 & 63;
    float2 a = P[x*66 + z], c = P[x*66 + z + 1];
    *(float4*)(cb + (((size_t)(b*64 + x)*64 + y)*64 + z)) = make_float4(a.x, a.y, c.x, c.y);
  }
}

__global__ __launch_bounds__(256) void k_fft_zy_inv(const float2* __restrict__ cin,
                                                    float* __restrict__ pos,
                                                    const void* __restrict__ xtraw, size_t xoff,
                                                    float* __restrict__ lsum,
                                                    const int* __restrict__ flag) {
  __shared__ float2 P[64*66];
  __shared__ float2 tw[64];
  __shared__ float red[256];
  int t = threadIdx.x;
  if (t < 64) { float s, c; __sincosf(-(PI2/64.f)*(float)t, &s, &c); tw[t] = make_float2(c, s); }
  size_t pb = (size_t)blockIdx.x * 4096;
  const float4* src = (const float4*)(cin + pb);
  #pragma unroll
  for (int i = 0; i < 8; ++i) {
    float4 v = src[t + 256*i];
    int idx2 = (t + 256*i) * 2;
    P[(idx2 >> 6)*66 + (idx2 & 63)]     = make_float2(v.x, v.y);
    P[(idx2 >> 6)*66 + (idx2 & 63) + 1] = make_float2(v.z, v.w);
  }
  __syncthreads();
  dft64<true>(P, tw, 1, 66);
  dft64<true>(P, tw, 66, 1);
  float* pdst = pos + pb;
  int bf = *flag;
  float lacc = 0.f;
  #pragma unroll
  for (int i = 0; i < 16; ++i) {
    int idx = t + 256*i;
    float np = pdst[idx] + P[(idx >> 6)*66 + (idx & 63)].x * (1.0f/(float)VOL);
    pdst[idx] = np;
    float xt = bf ? b2f(((const u16*)xtraw)[xoff + pb + idx])
                  : ((const float*)xtraw)[xoff + pb + idx];
    float d = xt - np;
    lacc = fmaf(d, d, lacc);
  }
  red[t] = lacc; __syncthreads();
  for (int s = 128; s > 0; s >>= 1) { if (t < s) red[t] += red[t+s]; __syncthreads(); }
  if (t == 0) atomicAdd(lsum, red[0]);
}

// ================= conv path (z-halo layout, row stride 66) =================
__global__ __launch_bounds__(256) void k_cellin(const float* __restrict__ pos,
                                                const float* __restrict__ delta,
                                                const float* __restrict__ Win,
                                                const float* __restrict__ binf,
                                                u16* __restrict__ ci) {
  int id = blockIdx.x * 256 + threadIdx.x;
  int z = id & 63, yy = (id >> 6) & 63, x = (id >> 12) & 63, b = id >> 18;
  float acc[8];
  #pragma unroll
  for (int c = 0; c < 8; ++c) acc[c] = binf[c];
  #pragma unroll 1
  for (int tap = 0; tap < 27; ++tap) {
    int kd = tap / 9, kh = (tap / 3) % 3, kw = tap % 3;
    int nx = x + kd - 1, ny = yy + kh - 1, nz = z + kw - 1;
    if ((unsigned)nx >= 64u || (unsigned)ny >= 64u || (unsigned)nz >= 64u) continue;
    size_t n = (((size_t)b * 64 + nx) * 64 + ny) * 64 + nz;
    float p = pos[n], d = delta[n];
    const float* w = Win + tap * 16;
    #pragma unroll
    for (int c = 0; c < 8; ++c) acc[c] = fmaf(p, w[c], fmaf(d, w[8 + c], acc[c]));
  }
  u16 hh[8];
  #pragma unroll
  for (int c = 0; c < 8; ++c) hh[c] = f2b(acc[c]);
  size_t rowbase = ((size_t)(b * 64 + x) * 64 + yy) * 66;
  *(uint4*)(ci + (rowbase + z + 1) * 8) = *(uint4*)hh;
  // re-zero halo slots (cb FFT alias corrupts them every iteration)
  uint4 zero = make_uint4(0, 0, 0, 0);
  if (z == 0)  *(uint4*)(ci + rowbase * 8) = zero;
  if (z == 63) *(uint4*)(ci + (rowbase + 65) * 8) = zero;
}

// MFMA ConvLSTM: 512 threads (8 waves), weights in LDS, halo A-loads
__global__ __launch_bounds__(512) void k_clstm(const u16* __restrict__ ci,
                                               const u16* __restrict__ hC,
                                               u16* __restrict__ hN,
                                               u16* __restrict__ c3u,
                                               const u16* __restrict__ Wf,
                                               const float* __restrict__ b3f) {
  __shared__ u16 wfl[13824];          // 27648 B
  __shared__ float zl[8][32][33];     // 33792 B
  int t = threadIdx.x;
  for (int i = t; i < 1728; i += 512) ((uint4*)wfl)[i] = ((const uint4*)Wf)[i];
  int wv = t >> 6, l = t & 63, ln = l & 31, hi = l >> 5;
  int bid = blockIdx.x;
  int x = bid & 63, yq = (bid >> 6) & 15, b = bid >> 10;
  int y = yq * 4 + (wv >> 1), z0 = (wv & 1) * 32;
  size_t cslot = ((size_t)(b * 64 + x) * 64 + y) * 66 + z0 + ln + 1;
  const u16* abase = (hi ? hC : ci) + cslot * 8;
  const u16* wbase = wfl + hi * 256 + ln * 8;
  __syncthreads();
  f32x16 acc;
  #pragma unroll
  for (int r = 0; r < 16; ++r) acc[r] = 0.f;
  #pragma unroll
  for (int tap = 0; tap < 27; ++tap) {
    const int dx = tap / 9 - 1, dy = (tap / 3) % 3 - 1, dz = tap % 3 - 1;
    int nx = x + dx, ny = y + dy;
    if ((unsigned)nx < 64u && (unsigned)ny < 64u) {
      bf16x8 wfr = __builtin_bit_cast(bf16x8, *(const uint4*)(wbase + tap * 512));
      bf16x8 afr = __builtin_bit_cast(bf16x8, *(const uint4*)(abase + (dx * 4224 + dy * 66 + dz) * 8));
      acc = __builtin_amdgcn_mfma_f32_32x32x16_bf16(afr, wfr, acc, 0, 0, 0);
    }
  }
  float bz = b3f[ln];
  #pragma unroll
  for (int r = 0; r < 16; ++r)
    zl[wv][(r & 3) + 8 * (r >> 2) + 4 * hi][ln] = acc[r] + bz;
  __syncthreads();
  uint2 cu = *(const uint2*)(c3u + cslot * 8 + hi * 4);
  const u16* cp = (const u16*)&cu;
  u16 cw[4], hw[4];
  #pragma unroll
  for (int q = 0; q < 4; ++q) {
    int cc = hi * 4 + q;
    float zi  = zl[wv][ln][cc];
    float zf  = zl[wv][ln][cc + 8];
    float zg  = zl[wv][ln][cc + 16];
    float zo_ = zl[wv][ln][cc + 24];
    float cn = fsig(zf) * b2f(cp[q]) + fsig(zi) * ftanh(zg);
    cw[q] = f2b(cn);
    hw[q] = f2b(fsig(zo_) * ftanh(cn));
  }
  *(uint2*)(c3u + cslot * 8 + hi * 4) = *(uint2*)cw;
  *(uint2*)(hN + cslot * 8 + hi * 4)  = *(uint2*)hw;
}

__global__ __launch_bounds__(256) void k_wout(const u16* __restrict__ h,
                                              const float* __restrict__ Wo,
                                              const float* __restrict__ bo,
                                              float* __restrict__ dpw) {
  int id = blockIdx.x * 256 + threadIdx.x;
  int z = id & 63, yy = (id >> 6) & 63, x = (id >> 12) & 63, b = id >> 18;
  size_t cslot = ((size_t)(b * 64 + x) * 64 + yy) * 66 + z + 1;
  float acc = bo[0];
  #pragma unroll 1
  for (int tap = 0; tap < 27; ++tap) {
    int kd = tap / 9, kh = (tap / 3) % 3, kw = tap % 3;
    int nx = x + kd - 1, ny = yy + kh - 1;
    if ((unsigned)nx >= 64u || (unsigned)ny >= 64u) continue;
    uint4 a = *(const uint4*)(h + (cslot + (size_t)((kd - 1) * 4224 + (kh - 1) * 66 + (kw - 1))) * 8);
    const u16* hp = (const u16*)&a;
    const float* w = Wo + tap * 8;
    #pragma unroll
    for (int c = 0; c < 8; ++c) acc = fmaf(b2f(hp[c]), w[c], acc);
  }
  dpw[id] = acc;
}

// ================= small dense LSTM branch =================
__global__ __launch_bounds__(256) void k_small(const float* __restrict__ psp,
                                               const float* __restrict__ psd,
                                               const float* __restrict__ cnts,
                                               const float* __restrict__ Wd1,
                                               const float* __restrict__ bd1,
                                               const float* __restrict__ Wlx,
                                               const float* __restrict__ Wlh,
                                               const float* __restrict__ bl,
                                               const float* __restrict__ Wd2,
                                               const float* __restrict__ bd2,
                                               const float* __restrict__ Wc1,
                                               const float* __restrict__ bc1,
                                               float* __restrict__ h1, float* __restrict__ c1,
                                               float* __restrict__ psn) {
  __shared__ float lp[128], x1[128], hs[128], zz[512], lps[66];
  int t = threadIdx.x, b = blockIdx.x;
  if (t < 64) {
    lp[t]      = __log10f(fmaxf(psp[b*64 + t] / cnts[t] * 8.0e6f, 1e-30f));
    lp[64 + t] = __log10f(fmaxf(psd[b*64 + t] / cnts[t] * 8.0e6f, 1e-30f));
  }
  if (t < 128) hs[t] = h1[b*128 + t];
  __syncthreads();
  if (t < 128) {
    float a = bd1[t];
    for (int j = 0; j < 128; ++j) a = fmaf(lp[j], Wd1[j*128 + t], a);
    x1[t] = a;
  }
  __syncthreads();
  for (int k = t; k < 512; k += 256) {
    float a = bl[k];
    for (int u = 0; u < 128; ++u)
      a = fmaf(x1[u], Wlx[u*512 + k], fmaf(hs[u], Wlh[u*512 + k], a));
    zz[k] = a;
  }
  __syncthreads();
  if (t < 128) {
    float cv = fsig(zz[128 + t]) * c1[b*128 + t] + fsig(zz[t]) * ftanh(zz[256 + t]);
    c1[b*128 + t] = cv;
    float hv = fsig(zz[384 + t]) * ftanh(cv);
    h1[b*128 + t] = hv; hs[t] = hv;
  }
  __syncthreads();
  if (t < 64) {
    float a = bd2[t];
    for (int u = 0; u < 128; ++u) a = fmaf(hs[u], Wd2[u*64 + t], a);
    lps[t + 1] = a;
  }
  __syncthreads();
  if (t < 64) {
    float a = fmaf(Wc1[1], lps[t + 1], bc1[0]);
    if (t > 0)  a = fmaf(Wc1[0], lps[t], a);
    if (t < 63) a = fmaf(Wc1[2], lps[t + 2], a);
    psn[b*64 + t] = __expf(a);
  }
}

// ================= output =================
__global__ __launch_bounds__(256) void k_out(const float* __restrict__ pos, void* __restrict__ outp,
                                             size_t eoff, const int* __restrict__ flag) {
  size_t i = (size_t)blockIdx.x * 256 + threadIdx.x;
  if (*flag) ((u16*)outp)[eoff + i] = f2b(pos[i]);
  else       ((float*)outp)[eoff + i] = pos[i];
}

__global__ void k_loss(const float* __restrict__ lsum, void* __restrict__ outp,
                       const int* __restrict__ flag) {
  float l = lsum[0] * (1.0f / (float)TOT);
  if (*flag) ((u16*)outp)[TOT] = f2b(l);
  else       ((float*)outp)[TOT] = l;
}

__global__ void k_sent(u16* __restrict__ outp) { outp[0] = f2b(1000.0f); }

extern "C" void kernel_launch(void* const* d_in, const int* in_sizes, int n_in,
                              void* d_out, int out_size, void* d_ws, size_t ws_size,
                              hipStream_t stream) {
  const void* x_init = d_in[0];
  const void* y      = d_in[1];
  const void* x_true = d_in[2];
  const int*  kbin   = (const int*)d_in[3];

  int nbs = 0;
  for (int cand = 8; cand >= 1; cand >>= 1) {
    size_t n1c = (size_t)cand * VOL;
    size_t slc = (size_t)cand * SLOTS1;
    size_t need = (4 * n1c + 171008 + 6912 + (size_t)cand * (192 + 256) + 96) * sizeof(float)
                + 4 * slc * 16;
    if (need <= ws_size) { nbs = cand; break; }
  }
  if (nbs == 0) { k_sent<<<1, 1, 0, stream>>>((u16*)d_out); return; }

  size_t n1 = (size_t)nbs * VOL;
  size_t sl = (size_t)nbs * SLOTS1;
  float* ws   = (float*)d_ws;
  float* pos  = ws;
  float* m    = pos + n1;
  float* v    = m + n1;
  float* dpw  = v + n1;
  u16*  c3u   = (u16*)(dpw + n1);     // sl*8 u16 each
  u16*  ci    = c3u + sl*8;
  u16*  hA    = ci + sl*8;
  u16*  hB    = hA + sl*8;
  float* wbuf = (float*)(hB + sl*8);  // 171008 f32
  u16*  Wf    = (u16*)(wbuf + 171008);// 13824 u16
  float* psp  = wbuf + 171008 + 6912;
  float* psd  = psp + (size_t)nbs*64;
  float* psn  = psd + (size_t)nbs*64;
  float* cnts = psn + (size_t)nbs*64;
  float* lsum = cnts + 64;            // 8
  float* h1   = lsum + 8;
  float* c1   = h1 + (size_t)nbs*128;
  int*   flag = (int*)(c1 + (size_t)nbs*128);

  float2* cb = (float2*)ci;           // alias: ci region; k_cellin re-zeroes halos each iter

  float* Win_f = wbuf + 0;     float* bin_f = wbuf + 432;
  float* b3_f  = wbuf + 14264; float* Wo_f  = wbuf + 14296;
  float* bo_f  = wbuf + 14512; float* Wd1_f = wbuf + 14513;
  float* bd1_f = wbuf + 30897; float* Wlx_f = wbuf + 31025;
  float* Wlh_f = wbuf + 96561; float* bl_f  = wbuf + 162097;
  float* Wd2_f = wbuf + 162609; float* bd2_f = wbuf + 170801;
  float* Wc1_f = wbuf + 170865; float* bc1_f = wbuf + 170868;

  const int CB = (int)(n1 / 256);

  k_sniff<<<1, 256, 0, stream>>>((const u16*)x_init, flag);
  k_cvtall<<<(WTOT + 255) / 256, 256, 0, stream>>>(
      d_in[4], d_in[5], d_in[6], d_in[7], d_in[8], d_in[9], d_in[10], d_in[11],
      d_in[12], d_in[13], d_in[14], d_in[15], d_in[16], d_in[17], d_in[18], d_in[19],
      wbuf, flag);
  k_mkwf<<<54, 256, 0, stream>>>(d_in[6], d_in[7], flag, Wf);
  hipMemsetAsync(cnts, 0, 72 * 4, stream);      // cnts + lsum
  k_counts<<<VOL / 256, 256, 0, stream>>>(kbin, cnts);

  for (int b0 = 0; b0 < NB; b0 += nbs) {
    hipMemsetAsync(c3u, 0, sl * 64, stream);    // c3u,ci,hA,hB contiguous
    hipMemsetAsync(h1, 0, (size_t)nbs * 256 * 4, stream);
    k_cvt<<<CB, 256, 0, stream>>>(x_init, (size_t)b0 * VOL, pos, flag);

    u16* hC = hA;
    u16* hN = hB;
    for (int t = 1; t <= 4; ++t) {
      float ib1 = (float)(1.0 / (1.0 - pow(0.9, (double)t)));
      float ib2 = (float)(1.0 / (1.0 - pow(0.999, (double)t)));

      hipMemsetAsync(psp, 0, (size_t)nbs * 128 * 4, stream);   // psp + psd
      k_fft_zy_adam<<<nbs * 64, 256, 0, stream>>>(pos, y, (size_t)b0 * VOL, m, v, dpw,
                                                  cb, ib1, ib2, t == 1, flag);
      k_fft_x_pow<<<nbs * 64, 256, 0, stream>>>(cb, kbin, psp);
      k_fft_zy<<<nbs * 64, 256, 0, stream>>>(dpw, cb);
      k_fft_x_pow<<<nbs * 64, 256, 0, stream>>>(cb, kbin, psd);

      k_cellin<<<CB, 256, 0, stream>>>(pos, dpw, Win_f, bin_f, ci);
      k_clstm<<<nbs * 1024, 512, 0, stream>>>(ci, hC, hN, c3u, Wf, b3_f);
      k_wout<<<CB, 256, 0, stream>>>(hN, Wo_f, bo_f, dpw);

      k_small<<<nbs, 256, 0, stream>>>(psp, psd, cnts, Wd1_f, bd1_f, Wlx_f, Wlh_f, bl_f,
                                       Wd2_f, bd2_f, Wc1_f, bc1_f, h1, c1, psn);

      k_fft_zy<<<nbs * 64, 256, 0, stream>>>(dpw, cb);
      k_fft_x_filt<<<nbs * 64, 256, 0, stream>>>(cb, kbin, psn);
      k_fft_zy_inv<<<nbs * 64, 256, 0, stream>>>(cb, pos, x_true, (size_t)b0 * VOL, lsum, flag);

      u16* tmp = hC; hC = hN; hN = tmp;
    }
    k_out<<<CB, 256, 0, stream>>>(pos, d_out, (size_t)b0 * VOL, flag);
  }
  k_loss<<<1, 1, 0, stream>>>(lsum, d_out, flag);
}

// Round 8
// 1439.998 us; speedup vs baseline: 4.1927x; 1.1174x over previous
//
#include <hip/hip_runtime.h>
#include <math.h>

#define NCC 64
#define NB 8
#define VOL (NCC*NCC*NCC)      // 262144 = 2^18
#define TOT (NB*VOL)           // 2097152
#define WTOT 170869            // total weight elements
#define PI2 6.2831853071795864769f
#define SLOTS1 270336          // 64*64*66 halo slots per batch

typedef unsigned short u16;
typedef __bf16 bf16x8 __attribute__((ext_vector_type(8)));
typedef float f32x16 __attribute__((ext_vector_type(16)));

__device__ __forceinline__ float b2f(u16 h){ return __uint_as_float(((unsigned)h)<<16); }
__device__ __forceinline__ u16 f2b(float f){
  unsigned u = __float_as_uint(f);
  unsigned r = (u + 0x7FFFu + ((u>>16)&1u)) >> 16;
  return (u16)r;
}
__device__ __forceinline__ float fsig(float x){ return 1.f / (1.f + __expf(-x)); }
__device__ __forceinline__ float ftanh(float x){
  float e = __expf(2.f * x);
  return 1.f - 2.f / (e + 1.f);
}

// ================= radix-8 FFT machinery =================
template<bool INV>
__device__ __forceinline__ void fft8(float2* x) {
  const float C = 0.70710678118654752440f;
  float2 s0,s1,s2,s3,s4,s5,s6,s7;
  s0 = make_float2(x[0].x + x[4].x, x[0].y + x[4].y);
  s4 = make_float2(x[0].x - x[4].x, x[0].y - x[4].y);
  s1 = make_float2(x[1].x + x[5].x, x[1].y + x[5].y);
  s5 = make_float2(x[1].x - x[5].x, x[1].y - x[5].y);
  s2 = make_float2(x[2].x + x[6].x, x[2].y + x[6].y);
  s6 = make_float2(x[2].x - x[6].x, x[2].y - x[6].y);
  s3 = make_float2(x[3].x + x[7].x, x[3].y + x[7].y);
  s7 = make_float2(x[3].x - x[7].x, x[3].y - x[7].y);
  float2 n5, n6, n7;
  if (!INV) {
    n5 = make_float2(C*(s5.x + s5.y), C*(s5.y - s5.x));
    n6 = make_float2(s6.y, -s6.x);
    n7 = make_float2(C*(s7.y - s7.x), -C*(s7.x + s7.y));
  } else {
    n5 = make_float2(C*(s5.x - s5.y), C*(s5.y + s5.x));
    n6 = make_float2(-s6.y, s6.x);
    n7 = make_float2(-C*(s7.x + s7.y), C*(s7.x - s7.y));
  }
  float2 t0,t1,t2,t3,t4,t5,t6,t7,d;
  t0 = make_float2(s0.x + s2.x, s0.y + s2.y);
  t2 = make_float2(s0.x - s2.x, s0.y - s2.y);
  t1 = make_float2(s1.x + s3.x, s1.y + s3.y);
  d  = make_float2(s1.x - s3.x, s1.y - s3.y);
  t3 = INV ? make_float2(-d.y, d.x) : make_float2(d.y, -d.x);
  t4 = make_float2(s4.x + n6.x, s4.y + n6.y);
  t6 = make_float2(s4.x - n6.x, s4.y - n6.y);
  t5 = make_float2(n5.x + n7.x, n5.y + n7.y);
  d  = make_float2(n5.x - n7.x, n5.y - n7.y);
  t7 = INV ? make_float2(-d.y, d.x) : make_float2(d.y, -d.x);
  x[0] = make_float2(t0.x + t1.x, t0.y + t1.y);
  x[1] = make_float2(t0.x - t1.x, t0.y - t1.y);
  x[2] = make_float2(t2.x + t3.x, t2.y + t3.y);
  x[3] = make_float2(t2.x - t3.x, t2.y - t3.y);
  x[4] = make_float2(t4.x + t5.x, t4.y + t5.y);
  x[5] = make_float2(t4.x - t5.x, t4.y - t5.y);
  x[6] = make_float2(t6.x + t7.x, t6.y + t7.y);
  x[7] = make_float2(t6.x - t7.x, t6.y - t7.y);
}

template<bool INV>
__device__ __forceinline__ void dft64(float2* Pf, const float2* tw, int ls, int ns) {
  const int BR[8] = {0,4,2,6,1,5,3,7};
  int t = threadIdx.x;
  int L0 = t >> 3, b = t & 7, L1 = L0 + 32;
  float2 v0[8], v1[8];
  #pragma unroll
  for (int a = 0; a < 8; ++a) v0[a] = Pf[L0*ls + (8*a + b)*ns];
  #pragma unroll
  for (int a = 0; a < 8; ++a) v1[a] = Pf[L1*ls + (8*a + b)*ns];
  __syncthreads();
  fft8<INV>(v0); fft8<INV>(v1);
  #pragma unroll
  for (int r = 0; r < 8; ++r) {
    float2 w = tw[(b * r) & 63];
    if (INV) w.y = -w.y;
    float2 a0 = v0[BR[r]], a1 = v1[BR[r]];
    Pf[L0*ls + (8*b + r)*ns] = make_float2(a0.x*w.x - a0.y*w.y, a0.x*w.y + a0.y*w.x);
    Pf[L1*ls + (8*b + r)*ns] = make_float2(a1.x*w.x - a1.y*w.y, a1.x*w.y + a1.y*w.x);
  }
  __syncthreads();
  int r = t & 7;
  #pragma unroll
  for (int q = 0; q < 8; ++q) v0[q] = Pf[L0*ls + (8*q + r)*ns];
  #pragma unroll
  for (int q = 0; q < 8; ++q) v1[q] = Pf[L1*ls + (8*q + r)*ns];
  fft8<INV>(v0); fft8<INV>(v1);
  #pragma unroll
  for (int j = 0; j < 8; ++j) {
    Pf[L0*ls + (8*BR[j] + r)*ns] = v0[j];
    Pf[L1*ls + (8*BR[j] + r)*ns] = v1[j];
  }
  __syncthreads();
}

// ================= setup kernels =================
__global__ __launch_bounds__(256) void k_sniff(const u16* __restrict__ x, int* __restrict__ flag) {
  __shared__ int cnt;
  if (threadIdx.x == 0) cnt = 0;
  __syncthreads();
  int sane = 0;
  for (int i = threadIdx.x; i < 1024; i += 256) {
    u16 h = x[2 * i];
    int e = (h >> 7) & 0xFF;
    if (h == 0 || (e >= 0x68 && e <= 0x8F)) sane++;
  }
  atomicAdd(&cnt, sane);
  __syncthreads();
  if (threadIdx.x == 0) flag[0] = (cnt >= 768) ? 1 : 0;
}

__global__ __launch_bounds__(256) void k_cvt(const void* __restrict__ in, size_t eoff,
                                             float* __restrict__ out, const int* __restrict__ flag) {
  size_t i = (size_t)blockIdx.x * 256 + threadIdx.x;
  if (*flag) out[i] = b2f(((const u16*)in)[eoff + i]);
  else       out[i] = ((const float*)in)[eoff + i];
}

__global__ __launch_bounds__(256) void k_cvtall(
    const void* s0, const void* s1, const void* s2, const void* s3,
    const void* s4, const void* s5, const void* s6, const void* s7,
    const void* s8, const void* s9, const void* s10, const void* s11,
    const void* s12, const void* s13, const void* s14, const void* s15,
    float* __restrict__ out, const int* __restrict__ flag) {
  const void* ps[16] = {s0,s1,s2,s3,s4,s5,s6,s7,s8,s9,s10,s11,s12,s13,s14,s15};
  const int offs[17] = {0,432,440,7352,14264,14296,14512,14513,30897,31025,
                        96561,162097,162609,170801,170865,170868,170869};
  int i = blockIdx.x * 256 + threadIdx.x;
  if (i >= WTOT) return;
  int s = 0;
  #pragma unroll
  for (int k = 1; k < 16; ++k) if (i >= offs[k]) s = k;
  int j = i - offs[s];
  if (*flag) out[i] = b2f(((const u16*)ps[s])[j]);
  else       out[i] = ((const float*)ps[s])[j];
}

// Wf[tap][hi][co][j] : u16 idx = tap*512 + hi*256 + co*8 + j
__global__ __launch_bounds__(256) void k_mkwf(const void* __restrict__ Wx, const void* __restrict__ Wh,
                                              const int* __restrict__ flag, u16* __restrict__ Wf) {
  int i = blockIdx.x * 256 + threadIdx.x;   // 13824
  if (i >= 13824) return;
  int j = i & 7, co = (i >> 3) & 31, hi = (i >> 8) & 1, tap = i >> 9;
  int src = tap * 256 + j * 32 + co;
  const void* P = hi ? Wh : Wx;
  u16 val;
  if (*flag) val = ((const u16*)P)[src];
  else       val = f2b(((const float*)P)[src]);
  Wf[i] = val;
}

__global__ __launch_bounds__(256) void k_counts(const int* __restrict__ kbin,
                                                float* __restrict__ cnts) {
  __shared__ float s[NCC];
  int t = threadIdx.x;
  if (t < NCC) s[t] = 0.f;
  __syncthreads();
  int i = blockIdx.x * 256 + t;
  atomicAdd(&s[kbin[i]], 1.f);
  __syncthreads();
  if (t < NCC) atomicAdd(&cnts[t], s[t]);
}

// ================= FFT kernels =================
__global__ __launch_bounds__(256) void k_fft_zy_adam(
    const float* __restrict__ pos, const void* __restrict__ yraw, size_t yoff,
    float* __restrict__ m, float* __restrict__ v, float* __restrict__ dpw,
    float2* __restrict__ cout, float ib1, float ib2, int first,
    const int* __restrict__ flag) {
  __shared__ float2 P[64*66];
  __shared__ float2 tw[64];
  int t = threadIdx.x;
  if (t < 64) { float s, c; __sincosf(-(PI2/64.f)*(float)t, &s, &c); tw[t] = make_float2(c, s); }
  size_t pb = (size_t)blockIdx.x * 4096;
  int bf = *flag;
  #pragma unroll
  for (int i = 0; i < 4; ++i) {
    int i4 = t + 256*i;
    float4 p4 = ((const float4*)(pos + pb))[i4];
    float yv[4];
    if (bf) {
      uint2 yu = ((const uint2*)((const u16*)yraw + yoff + pb))[i4];
      const u16* yp = (const u16*)&yu;
      yv[0]=b2f(yp[0]); yv[1]=b2f(yp[1]); yv[2]=b2f(yp[2]); yv[3]=b2f(yp[3]);
    } else {
      float4 y4 = ((const float4*)((const float*)yraw + yoff + pb))[i4];
      yv[0]=y4.x; yv[1]=y4.y; yv[2]=y4.z; yv[3]=y4.w;
    }
    float pv[4] = {p4.x, p4.y, p4.z, p4.w};
    float mo[4], vo[4], dd[4];
    if (!first) {
      float4 m4 = ((const float4*)(m + pb))[i4];
      float4 v4 = ((const float4*)(v + pb))[i4];
      mo[0]=m4.x; mo[1]=m4.y; mo[2]=m4.z; mo[3]=m4.w;
      vo[0]=v4.x; vo[1]=v4.y; vo[2]=v4.z; vo[3]=v4.w;
    }
    #pragma unroll
    for (int c = 0; c < 4; ++c) {
      float g = pv[c] - yv[c];
      float mi = first ? 0.1f*g : 0.9f*mo[c] + 0.1f*g;
      float vi = first ? 0.001f*g*g : 0.999f*vo[c] + 0.001f*g*g;
      mo[c] = mi; vo[c] = vi;
      dd[c] = -0.1f * (mi * ib1) / (sqrtf(vi * ib2) + 1e-7f);
    }
    ((float4*)(m + pb))[i4]   = make_float4(mo[0], mo[1], mo[2], mo[3]);
    ((float4*)(v + pb))[i4]   = make_float4(vo[0], vo[1], vo[2], vo[3]);
    ((float4*)(dpw + pb))[i4] = make_float4(dd[0], dd[1], dd[2], dd[3]);
    int base = i4 * 4;
    float2* row = P + (base >> 6)*66 + (base & 63);
    row[0] = make_float2(pv[0], 0.f);
    row[1] = make_float2(pv[1], 0.f);
    row[2] = make_float2(pv[2], 0.f);
    row[3] = make_float2(pv[3], 0.f);
  }
  __syncthreads();
  dft64<false>(P, tw, 66, 1);
  dft64<false>(P, tw, 1, 66);
  float4* dst = (float4*)(cout + pb);
  #pragma unroll
  for (int i = 0; i < 8; ++i) {
    int idx2 = (t + 256*i) * 2;
    float2 a = P[(idx2 >> 6)*66 + (idx2 & 63)];
    float2 b = P[(idx2 >> 6)*66 + (idx2 & 63) + 1];
    dst[t + 256*i] = make_float4(a.x, a.y, b.x, b.y);
  }
}

__global__ __launch_bounds__(256) void k_fft_zy(const float* __restrict__ rin,
                                                float2* __restrict__ cout) {
  __shared__ float2 P[64*66];
  __shared__ float2 tw[64];
  int t = threadIdx.x;
  if (t < 64) { float s, c; __sincosf(-(PI2/64.f)*(float)t, &s, &c); tw[t] = make_float2(c, s); }
  const float* src = rin + (size_t)blockIdx.x * 4096;
  #pragma unroll
  for (int i = 0; i < 4; ++i) {
    float4 v = ((const float4*)src)[t + 256*i];
    int base = (t + 256*i) * 4;
    float2* row = P + (base >> 6)*66 + (base & 63);
    row[0] = make_float2(v.x, 0.f);
    row[1] = make_float2(v.y, 0.f);
    row[2] = make_float2(v.z, 0.f);
    row[3] = make_float2(v.w, 0.f);
  }
  __syncthreads();
  dft64<false>(P, tw, 66, 1);
  dft64<false>(P, tw, 1, 66);
  float4* dst = (float4*)(cout + (size_t)blockIdx.x * 4096);
  #pragma unroll
  for (int i = 0; i < 8; ++i) {
    int idx2 = (t + 256*i) * 2;
    float2 a = P[(idx2 >> 6)*66 + (idx2 & 63)];
    float2 b = P[(idx2 >> 6)*66 + (idx2 & 63) + 1];
    dst[t + 256*i] = make_float4(a.x, a.y, b.x, b.y);
  }
}

__global__ __launch_bounds__(256) void k_fft_x_pow(const float2* __restrict__ cin,
                                                   const int* __restrict__ kb,
                                                   float* __restrict__ psum) {
  __shared__ float2 P[64*66];
  __shared__ float2 tw[64];
  __shared__ float pb[64];
  int t = threadIdx.x;
  if (t < 64) { float s, c; __sincosf(-(PI2/64.f)*(float)t, &s, &c); tw[t] = make_float2(c, s); pb[t] = 0.f; }
  int b = blockIdx.x >> 6, y = blockIdx.x & 63;
  #pragma unroll
  for (int i = 0; i < 8; ++i) {
    int idx2 = (t + 256*i) * 2;
    int x = idx2 >> 6, z = idx2 & 63;
    float4 v = *(const float4*)(cin + (((size_t)(b*64 + x)*64 + y)*64 + z));
    P[x*66 + z]     = make_float2(v.x, v.y);
    P[x*66 + z + 1] = make_float2(v.z, v.w);
  }
  __syncthreads();
  dft64<false>(P, tw, 1, 66);
  const float INV2 = 1.0f / ((float)VOL * (float)VOL);
  #pragma unroll
  for (int i = 0; i < 16; ++i) {
    int idx = t + 256*i;
    int x = idx >> 6, z = idx & 63;
    float2 a = P[x*66 + z];
    float pm = (a.x*a.x + a.y*a.y) * INV2;
    atomicAdd(&pb[kb[(x*64 + y)*64 + z]], pm);
  }
  __syncthreads();
  if (t < 64) atomicAdd(&psum[b*64 + t], pb[t]);
}

__global__ __launch_bounds__(256) void k_fft_x_filt(float2* __restrict__ cb,
                                                    const int* __restrict__ kb,
                                                    const float* __restrict__ psn) {
  __shared__ float2 P[64*66];
  __shared__ float2 tw[64];
  int t = threadIdx.x;
  if (t < 64) { float s, c; __sincosf(-(PI2/64.f)*(float)t, &s, &c); tw[t] = make_float2(c, s); }
  int b = blockIdx.x >> 6, y = blockIdx.x & 63;
  #pragma unroll
  for (int i = 0; i < 8; ++i) {
    int idx2 = (t + 256*i) * 2;
    int x = idx2 >> 6, z = idx2 & 63;
    float4 v = *(const float4*)(cb + (((size_t)(b*64 + x)*64 + y)*64 + z));
    P[x*66 + z]     = make_float2(v.x, v.y);
    P[x*66 + z + 1] = make_float2(v.z, v.w);
  }
  __syncthreads();
  dft64<false>(P, tw, 1, 66);
  #pragma unroll
  for (int i = 0; i < 16; ++i) {
    int idx = t + 256*i;
    int x = idx >> 6, z = idx & 63;
    float fac = sqrtf(psn[b*64 + kb[(x*64 + y)*64 + z]]);
    float2 a = P[x*66 + z];
    P[x*66 + z] = make_float2(a.x * fac, a.y * fac);
  }
  __syncthreads();
  dft64<true>(P, tw, 1, 66);
  #pragma unroll
  for (int i = 0; i < 8; ++i) {
    int idx2 = (t + 256*i) * 2;
    int x = idx2 >> 6, z = idx2 & 63;
    float2 a = P[x*66 + z], c = P[x*66 + z + 1];
    *(float4*)(cb + (((size_t)(b*64 + x)*64 + y)*64 + z)) = make_float4(a.x, a.y, c.x, c.y);
  }
}

__global__ __launch_bounds__(256) void k_fft_zy_inv(const float2* __restrict__ cin,
                                                    float* __restrict__ pos,
                                                    const void* __restrict__ xtraw, size_t xoff,
                                                    float* __restrict__ lsum,
                                                    const int* __restrict__ flag) {
  __shared__ float2 P[64*66];
  __shared__ float2 tw[64];
  __shared__ float red[256];
  int t = threadIdx.x;
  if (t < 64) { float s, c; __sincosf(-(PI2/64.f)*(float)t, &s, &c); tw[t] = make_float2(c, s); }
  size_t pb = (size_t)blockIdx.x * 4096;
  const float4* src = (const float4*)(cin + pb);
  #pragma unroll
  for (int i = 0; i < 8; ++i) {
    float4 v = src[t + 256*i];
    int idx2 = (t + 256*i) * 2;
    P[(idx2 >> 6)*66 + (idx2 & 63)]     = make_float2(v.x, v.y);
    P[(idx2 >> 6)*66 + (idx2 & 63) + 1] = make_float2(v.z, v.w);
  }
  __syncthreads();
  dft64<true>(P, tw, 1, 66);
  dft64<true>(P, tw, 66, 1);
  float* pdst = pos + pb;
  int bf = *flag;
  float lacc = 0.f;
  #pragma unroll
  for (int i = 0; i < 16; ++i) {
    int idx = t + 256*i;
    float np = pdst[idx] + P[(idx >> 6)*66 + (idx & 63)].x * (1.0f/(float)VOL);
    pdst[idx] = np;
    float xt = bf ? b2f(((const u16*)xtraw)[xoff + pb + idx])
                  : ((const float*)xtraw)[xoff + pb + idx];
    float d = xt - np;
    lacc = fmaf(d, d, lacc);
  }
  red[t] = lacc; __syncthreads();
  for (int s = 128; s > 0; s >>= 1) { if (t < s) red[t] += red[t+s]; __syncthreads(); }
  if (t == 0) atomicAdd(lsum, red[0]);
}

// ================= conv path (z-halo layout, row stride 66) =================
__global__ __launch_bounds__(256) void k_cellin(const float* __restrict__ pos,
                                                const float* __restrict__ delta,
                                                const float* __restrict__ Win,
                                                const float* __restrict__ binf,
                                                u16* __restrict__ ci) {
  int id = blockIdx.x * 256 + threadIdx.x;
  int z = id & 63, yy = (id >> 6) & 63, x = (id >> 12) & 63, b = id >> 18;
  float acc[8];
  #pragma unroll
  for (int c = 0; c < 8; ++c) acc[c] = binf[c];
  #pragma unroll 1
  for (int tap = 0; tap < 27; ++tap) {
    int kd = tap / 9, kh = (tap / 3) % 3, kw = tap % 3;
    int nx = x + kd - 1, ny = yy + kh - 1, nz = z + kw - 1;
    if ((unsigned)nx >= 64u || (unsigned)ny >= 64u || (unsigned)nz >= 64u) continue;
    size_t n = (((size_t)b * 64 + nx) * 64 + ny) * 64 + nz;
    float p = pos[n], d = delta[n];
    const float* w = Win + tap * 16;
    #pragma unroll
    for (int c = 0; c < 8; ++c) acc[c] = fmaf(p, w[c], fmaf(d, w[8 + c], acc[c]));
  }
  u16 hh[8];
  #pragma unroll
  for (int c = 0; c < 8; ++c) hh[c] = f2b(acc[c]);
  size_t rowbase = ((size_t)(b * 64 + x) * 64 + yy) * 66;
  *(uint4*)(ci + (rowbase + z + 1) * 8) = *(uint4*)hh;
  // re-zero halo slots (cb FFT alias corrupts them every iteration)
  uint4 zero = make_uint4(0, 0, 0, 0);
  if (z == 0)  *(uint4*)(ci + rowbase * 8) = zero;
  if (z == 63) *(uint4*)(ci + (rowbase + 65) * 8) = zero;
}

// MFMA ConvLSTM: swapped operands (W as A, act as B) -> register-local gate epilogue
__global__ __launch_bounds__(512, 8) void k_clstm(const u16* __restrict__ ci,
                                                  const u16* __restrict__ hC,
                                                  u16* __restrict__ hN,
                                                  u16* __restrict__ c3u,
                                                  const u16* __restrict__ Wf,
                                                  const float* __restrict__ b3f) {
  __shared__ u16 wfl[13824];          // 27648 B (only LDS)
  int t = threadIdx.x;
  for (int i = t; i < 1728; i += 512) ((uint4*)wfl)[i] = ((const uint4*)Wf)[i];
  int wv = t >> 6, l = t & 63, ln = l & 31, hi = l >> 5;
  int bid = blockIdx.x;
  int x = bid & 63, yq = (bid >> 6) & 15, b = bid >> 10;
  int y = yq * 4 + (wv >> 1), z0 = (wv & 1) * 32;
  size_t cslot = ((size_t)(b * 64 + x) * 64 + y) * 66 + z0 + ln + 1;
  const u16* abase = (hi ? hC : ci) + cslot * 8;
  const u16* wbase = wfl + hi * 256 + ln * 8;
  __syncthreads();
  f32x16 acc;
  #pragma unroll
  for (int r = 0; r < 16; ++r) acc[r] = 0.f;
  #pragma unroll
  for (int tap = 0; tap < 27; ++tap) {
    const int dx = tap / 9 - 1, dy = (tap / 3) % 3 - 1, dz = tap % 3 - 1;
    int nx = x + dx, ny = y + dy;
    if ((unsigned)nx < 64u && (unsigned)ny < 64u) {
      bf16x8 wfr = __builtin_bit_cast(bf16x8, *(const uint4*)(wbase + tap * 512));
      bf16x8 afr = __builtin_bit_cast(bf16x8, *(const uint4*)(abase + (dx * 4224 + dy * 66 + dz) * 8));
      acc = __builtin_amdgcn_mfma_f32_32x32x16_bf16(wfr, afr, acc, 0, 0, 0);
    }
  }
  // D[co][voxel]: lane (ln,hi) holds voxel=ln, co = (r&3) + 8*(r>>2) + 4*hi
  float4 bi  = *(const float4*)(b3f + 4 * hi);
  float4 bff = *(const float4*)(b3f + 8 + 4 * hi);
  float4 bg  = *(const float4*)(b3f + 16 + 4 * hi);
  float4 bo_ = *(const float4*)(b3f + 24 + 4 * hi);
  const float* bip = (const float*)&bi;
  const float* bfp = (const float*)&bff;
  const float* bgp = (const float*)&bg;
  const float* bop = (const float*)&bo_;
  uint2 cu = *(const uint2*)(c3u + cslot * 8 + hi * 4);
  const u16* cp = (const u16*)&cu;
  u16 cw[4], hw[4];
  #pragma unroll
  for (int q = 0; q < 4; ++q) {
    float zi  = acc[q]      + bip[q];
    float zf  = acc[4 + q]  + bfp[q];
    float zg  = acc[8 + q]  + bgp[q];
    float zo_ = acc[12 + q] + bop[q];
    float cn = fsig(zf) * b2f(cp[q]) + fsig(zi) * ftanh(zg);
    cw[q] = f2b(cn);
    hw[q] = f2b(fsig(zo_) * ftanh(cn));
  }
  *(uint2*)(c3u + cslot * 8 + hi * 4) = *(uint2*)cw;
  *(uint2*)(hN + cslot * 8 + hi * 4)  = *(uint2*)hw;
}

__global__ __launch_bounds__(256) void k_wout(const u16* __restrict__ h,
                                              const float* __restrict__ Wo,
                                              const float* __restrict__ bo,
                                              float* __restrict__ dpw) {
  int id = blockIdx.x * 256 + threadIdx.x;
  int z = id & 63, yy = (id >> 6) & 63, x = (id >> 12) & 63, b = id >> 18;
  size_t cslot = ((size_t)(b * 64 + x) * 64 + yy) * 66 + z + 1;
  float acc = bo[0];
  #pragma unroll 1
  for (int tap = 0; tap < 27; ++tap) {
    int kd = tap / 9, kh = (tap / 3) % 3, kw = tap % 3;
    int nx = x + kd - 1, ny = yy + kh - 1;
    if ((unsigned)nx >= 64u || (unsigned)ny >= 64u) continue;
    uint4 a = *(const uint4*)(h + (cslot + (size_t)((kd - 1) * 4224 + (kh - 1) * 66 + (kw - 1))) * 8);
    const u16* hp = (const u16*)&a;
    const float* w = Wo + tap * 8;
    #pragma unroll
    for (int c = 0; c < 8; ++c) acc = fmaf(b2f(hp[c]), w[c], acc);
  }
  dpw[id] = acc;
}

// ================= small dense LSTM branch =================
__global__ __launch_bounds__(256) void k_small(const float* __restrict__ psp,
                                               const float* __restrict__ psd,
                                               const float* __restrict__ cnts,
                                               const float* __restrict__ Wd1,
                                               const float* __restrict__ bd1,
                                               const float* __restrict__ Wlx,
                                               const float* __restrict__ Wlh,
                                               const float* __restrict__ bl,
                                               const float* __restrict__ Wd2,
                                               const float* __restrict__ bd2,
                                               const float* __restrict__ Wc1,
                                               const float* __restrict__ bc1,
                                               float* __restrict__ h1, float* __restrict__ c1,
                                               float* __restrict__ psn) {
  __shared__ float lp[128], x1[128], hs[128], zz[512], lps[66];
  int t = threadIdx.x, b = blockIdx.x;
  if (t < 64) {
    lp[t]      = __log10f(fmaxf(psp[b*64 + t] / cnts[t] * 8.0e6f, 1e-30f));
    lp[64 + t] = __log10f(fmaxf(psd[b*64 + t] / cnts[t] * 8.0e6f, 1e-30f));
  }
  if (t < 128) hs[t] = h1[b*128 + t];
  __syncthreads();
  if (t < 128) {
    float a = bd1[t];
    for (int j = 0; j < 128; ++j) a = fmaf(lp[j], Wd1[j*128 + t], a);
    x1[t] = a;
  }
  __syncthreads();
  for (int k = t; k < 512; k += 256) {
    float a = bl[k];
    for (int u = 0; u < 128; ++u)
      a = fmaf(x1[u], Wlx[u*512 + k], fmaf(hs[u], Wlh[u*512 + k], a));
    zz[k] = a;
  }
  __syncthreads();
  if (t < 128) {
    float cv = fsig(zz[128 + t]) * c1[b*128 + t] + fsig(zz[t]) * ftanh(zz[256 + t]);
    c1[b*128 + t] = cv;
    float hv = fsig(zz[384 + t]) * ftanh(cv);
    h1[b*128 + t] = hv; hs[t] = hv;
  }
  __syncthreads();
  if (t < 64) {
    float a = bd2[t];
    for (int u = 0; u < 128; ++u) a = fmaf(hs[u], Wd2[u*64 + t], a);
    lps[t + 1] = a;
  }
  __syncthreads();
  if (t < 64) {
    float a = fmaf(Wc1[1], lps[t + 1], bc1[0]);
    if (t > 0)  a = fmaf(Wc1[0], lps[t], a);
    if (t < 63) a = fmaf(Wc1[2], lps[t + 2], a);
    psn[b*64 + t] = __expf(a);
  }
}

// ================= output =================
__global__ __launch_bounds__(256) void k_out(const float* __restrict__ pos, void* __restrict__ outp,
                                             size_t eoff, const int* __restrict__ flag) {
  size_t i = (size_t)blockIdx.x * 256 + threadIdx.x;
  if (*flag) ((u16*)outp)[eoff + i] = f2b(pos[i]);
  else       ((float*)outp)[eoff + i] = pos[i];
}

__global__ void k_loss(const float* __restrict__ lsum, void* __restrict__ outp,
                       const int* __restrict__ flag) {
  float l = lsum[0] * (1.0f / (float)TOT);
  if (*flag) ((u16*)outp)[TOT] = f2b(l);
  else       ((float*)outp)[TOT] = l;
}

__global__ void k_sent(u16* __restrict__ outp) { outp[0] = f2b(1000.0f); }

extern "C" void kernel_launch(void* const* d_in, const int* in_sizes, int n_in,
                              void* d_out, int out_size, void* d_ws, size_t ws_size,
                              hipStream_t stream) {
  const void* x_init = d_in[0];
  const void* y      = d_in[1];
  const void* x_true = d_in[2];
  const int*  kbin   = (const int*)d_in[3];

  int nbs = 0;
  for (int cand = 8; cand >= 1; cand >>= 1) {
    size_t n1c = (size_t)cand * VOL;
    size_t slc = (size_t)cand * SLOTS1;
    size_t need = (4 * n1c + 171008 + 6912 + (size_t)cand * (192 + 256) + 96) * sizeof(float)
                + 4 * slc * 16;
    if (need <= ws_size) { nbs = cand; break; }
  }
  if (nbs == 0) { k_sent<<<1, 1, 0, stream>>>((u16*)d_out); return; }

  size_t n1 = (size_t)nbs * VOL;
  size_t sl = (size_t)nbs * SLOTS1;
  float* ws   = (float*)d_ws;
  float* pos  = ws;
  float* m    = pos + n1;
  float* v    = m + n1;
  float* dpw  = v + n1;
  u16*  c3u   = (u16*)(dpw + n1);     // sl*8 u16 each
  u16*  ci    = c3u + sl*8;
  u16*  hA    = ci + sl*8;
  u16*  hB    = hA + sl*8;
  float* wbuf = (float*)(hB + sl*8);  // 171008 f32
  u16*  Wf    = (u16*)(wbuf + 171008);// 13824 u16
  float* psp  = wbuf + 171008 + 6912;
  float* psd  = psp + (size_t)nbs*64;
  float* psn  = psd + (size_t)nbs*64;
  float* cnts = psn + (size_t)nbs*64;
  float* lsum = cnts + 64;            // 8
  float* h1   = lsum + 8;
  float* c1   = h1 + (size_t)nbs*128;
  int*   flag = (int*)(c1 + (size_t)nbs*128);

  float2* cb = (float2*)ci;           // alias: ci region; k_cellin re-zeroes halos each iter

  float* Win_f = wbuf + 0;     float* bin_f = wbuf + 432;
  float* b3_f  = wbuf + 14264; float* Wo_f  = wbuf + 14296;
  float* bo_f  = wbuf + 14512; float* Wd1_f = wbuf + 14513;
  float* bd1_f = wbuf + 30897; float* Wlx_f = wbuf + 31025;
  float* Wlh_f = wbuf + 96561; float* bl_f  = wbuf + 162097;
  float* Wd2_f = wbuf + 162609; float* bd2_f = wbuf + 170801;
  float* Wc1_f = wbuf + 170865; float* bc1_f = wbuf + 170868;

  const int CB = (int)(n1 / 256);

  k_sniff<<<1, 256, 0, stream>>>((const u16*)x_init, flag);
  k_cvtall<<<(WTOT + 255) / 256, 256, 0, stream>>>(
      d_in[4], d_in[5], d_in[6], d_in[7], d_in[8], d_in[9], d_in[10], d_in[11],
      d_in[12], d_in[13], d_in[14], d_in[15], d_in[16], d_in[17], d_in[18], d_in[19],
      wbuf, flag);
  k_mkwf<<<54, 256, 0, stream>>>(d_in[6], d_in[7], flag, Wf);
  hipMemsetAsync(cnts, 0, 72 * 4, stream);      // cnts + lsum
  k_counts<<<VOL / 256, 256, 0, stream>>>(kbin, cnts);

  for (int b0 = 0; b0 < NB; b0 += nbs) {
    hipMemsetAsync(c3u, 0, sl * 64, stream);    // c3u,ci,hA,hB contiguous
    hipMemsetAsync(h1, 0, (size_t)nbs * 256 * 4, stream);
    k_cvt<<<CB, 256, 0, stream>>>(x_init, (size_t)b0 * VOL, pos, flag);

    u16* hC = hA;
    u16* hN = hB;
    for (int t = 1; t <= 4; ++t) {
      float ib1 = (float)(1.0 / (1.0 - pow(0.9, (double)t)));
      float ib2 = (float)(1.0 / (1.0 - pow(0.999, (double)t)));

      hipMemsetAsync(psp, 0, (size_t)nbs * 128 * 4, stream);   // psp + psd
      k_fft_zy_adam<<<nbs * 64, 256, 0, stream>>>(pos, y, (size_t)b0 * VOL, m, v, dpw,
                                                  cb, ib1, ib2, t == 1, flag);
      k_fft_x_pow<<<nbs * 64, 256, 0, stream>>>(cb, kbin, psp);
      k_fft_zy<<<nbs * 64, 256, 0, stream>>>(dpw, cb);
      k_fft_x_pow<<<nbs * 64, 256, 0, stream>>>(cb, kbin, psd);

      k_cellin<<<CB, 256, 0, stream>>>(pos, dpw, Win_f, bin_f, ci);
      k_clstm<<<nbs * 1024, 512, 0, stream>>>(ci, hC, hN, c3u, Wf, b3_f);
      k_wout<<<CB, 256, 0, stream>>>(hN, Wo_f, bo_f, dpw);

      k_small<<<nbs, 256, 0, stream>>>(psp, psd, cnts, Wd1_f, bd1_f, Wlx_f, Wlh_f, bl_f,
                                       Wd2_f, bd2_f, Wc1_f, bc1_f, h1, c1, psn);

      k_fft_zy<<<nbs * 64, 256, 0, stream>>>(dpw, cb);
      k_fft_x_filt<<<nbs * 64, 256, 0, stream>>>(cb, kbin, psn);
      k_fft_zy_inv<<<nbs * 64, 256, 0, stream>>>(cb, pos, x_true, (size_t)b0 * VOL, lsum, flag);

      u16* tmp = hC; hC = hN; hN = tmp;
    }
    k_out<<<CB, 256, 0, stream>>>(pos, d_out, (size_t)b0 * VOL, flag);
  }
  k_loss<<<1, 1, 0, stream>>>(lsum, d_out, flag);
}

// Round 9
// 1352.810 us; speedup vs baseline: 4.4629x; 1.0644x over previous
//
#include <hip/hip_runtime.h>
#include <math.h>

#define NCC 64
#define NB 8
#define VOL (NCC*NCC*NCC)      // 262144 = 2^18
#define TOT (NB*VOL)           // 2097152
#define WTOT 170869            // total weight elements
#define PI2 6.2831853071795864769f
#define HS 287496              // 66*66*66 halo slots per batch elem
#define SX 4356                // 66*66

typedef unsigned short u16;
typedef __bf16 bf16x8 __attribute__((ext_vector_type(8)));
typedef float f32x16 __attribute__((ext_vector_type(16)));

__device__ __forceinline__ float b2f(u16 h){ return __uint_as_float(((unsigned)h)<<16); }
__device__ __forceinline__ u16 f2b(float f){
  unsigned u = __float_as_uint(f);
  unsigned r = (u + 0x7FFFu + ((u>>16)&1u)) >> 16;
  return (u16)r;
}
__device__ __forceinline__ float fsig(float x){ return 1.f / (1.f + __expf(-x)); }
__device__ __forceinline__ float ftanh(float x){
  float e = __expf(2.f * x);
  return 1.f - 2.f / (e + 1.f);
}

// ================= radix-8 FFT machinery =================
template<bool INV>
__device__ __forceinline__ void fft8(float2* x) {
  const float C = 0.70710678118654752440f;
  float2 s0,s1,s2,s3,s4,s5,s6,s7;
  s0 = make_float2(x[0].x + x[4].x, x[0].y + x[4].y);
  s4 = make_float2(x[0].x - x[4].x, x[0].y - x[4].y);
  s1 = make_float2(x[1].x + x[5].x, x[1].y + x[5].y);
  s5 = make_float2(x[1].x - x[5].x, x[1].y - x[5].y);
  s2 = make_float2(x[2].x + x[6].x, x[2].y + x[6].y);
  s6 = make_float2(x[2].x - x[6].x, x[2].y - x[6].y);
  s3 = make_float2(x[3].x + x[7].x, x[3].y + x[7].y);
  s7 = make_float2(x[3].x - x[7].x, x[3].y - x[7].y);
  float2 n5, n6, n7;
  if (!INV) {
    n5 = make_float2(C*(s5.x + s5.y), C*(s5.y - s5.x));
    n6 = make_float2(s6.y, -s6.x);
    n7 = make_float2(C*(s7.y - s7.x), -C*(s7.x + s7.y));
  } else {
    n5 = make_float2(C*(s5.x - s5.y), C*(s5.y + s5.x));
    n6 = make_float2(-s6.y, s6.x);
    n7 = make_float2(-C*(s7.x + s7.y), C*(s7.x - s7.y));
  }
  float2 t0,t1,t2,t3,t4,t5,t6,t7,d;
  t0 = make_float2(s0.x + s2.x, s0.y + s2.y);
  t2 = make_float2(s0.x - s2.x, s0.y - s2.y);
  t1 = make_float2(s1.x + s3.x, s1.y + s3.y);
  d  = make_float2(s1.x - s3.x, s1.y - s3.y);
  t3 = INV ? make_float2(-d.y, d.x) : make_float2(d.y, -d.x);
  t4 = make_float2(s4.x + n6.x, s4.y + n6.y);
  t6 = make_float2(s4.x - n6.x, s4.y - n6.y);
  t5 = make_float2(n5.x + n7.x, n5.y + n7.y);
  d  = make_float2(n5.x - n7.x, n5.y - n7.y);
  t7 = INV ? make_float2(-d.y, d.x) : make_float2(d.y, -d.x);
  x[0] = make_float2(t0.x + t1.x, t0.y + t1.y);
  x[1] = make_float2(t0.x - t1.x, t0.y - t1.y);
  x[2] = make_float2(t2.x + t3.x, t2.y + t3.y);
  x[3] = make_float2(t2.x - t3.x, t2.y - t3.y);
  x[4] = make_float2(t4.x + t5.x, t4.y + t5.y);
  x[5] = make_float2(t4.x - t5.x, t4.y - t5.y);
  x[6] = make_float2(t6.x + t7.x, t6.y + t7.y);
  x[7] = make_float2(t6.x - t7.x, t6.y - t7.y);
}

template<bool INV>
__device__ __forceinline__ void dft64(float2* Pf, const float2* tw, int ls, int ns) {
  const int BR[8] = {0,4,2,6,1,5,3,7};
  int t = threadIdx.x;
  int L0 = t >> 3, b = t & 7, L1 = L0 + 32;
  float2 v0[8], v1[8];
  #pragma unroll
  for (int a = 0; a < 8; ++a) v0[a] = Pf[L0*ls + (8*a + b)*ns];
  #pragma unroll
  for (int a = 0; a < 8; ++a) v1[a] = Pf[L1*ls + (8*a + b)*ns];
  __syncthreads();
  fft8<INV>(v0); fft8<INV>(v1);
  #pragma unroll
  for (int r = 0; r < 8; ++r) {
    float2 w = tw[(b * r) & 63];
    if (INV) w.y = -w.y;
    float2 a0 = v0[BR[r]], a1 = v1[BR[r]];
    Pf[L0*ls + (8*b + r)*ns] = make_float2(a0.x*w.x - a0.y*w.y, a0.x*w.y + a0.y*w.x);
    Pf[L1*ls + (8*b + r)*ns] = make_float2(a1.x*w.x - a1.y*w.y, a1.x*w.y + a1.y*w.x);
  }
  __syncthreads();
  int r = t & 7;
  #pragma unroll
  for (int q = 0; q < 8; ++q) v0[q] = Pf[L0*ls + (8*q + r)*ns];
  #pragma unroll
  for (int q = 0; q < 8; ++q) v1[q] = Pf[L1*ls + (8*q + r)*ns];
  fft8<INV>(v0); fft8<INV>(v1);
  #pragma unroll
  for (int j = 0; j < 8; ++j) {
    Pf[L0*ls + (8*BR[j] + r)*ns] = v0[j];
    Pf[L1*ls + (8*BR[j] + r)*ns] = v1[j];
  }
  __syncthreads();
}

// ================= setup kernels =================
__global__ __launch_bounds__(256) void k_sniff(const u16* __restrict__ x, int* __restrict__ flag) {
  __shared__ int cnt;
  if (threadIdx.x == 0) cnt = 0;
  __syncthreads();
  int sane = 0;
  for (int i = threadIdx.x; i < 1024; i += 256) {
    u16 h = x[2 * i];
    int e = (h >> 7) & 0xFF;
    if (h == 0 || (e >= 0x68 && e <= 0x8F)) sane++;
  }
  atomicAdd(&cnt, sane);
  __syncthreads();
  if (threadIdx.x == 0) flag[0] = (cnt >= 768) ? 1 : 0;
}

__global__ __launch_bounds__(256) void k_cvt(const void* __restrict__ in, size_t eoff,
                                             float* __restrict__ out, const int* __restrict__ flag) {
  size_t i = (size_t)blockIdx.x * 256 + threadIdx.x;
  if (*flag) out[i] = b2f(((const u16*)in)[eoff + i]);
  else       out[i] = ((const float*)in)[eoff + i];
}

__global__ __launch_bounds__(256) void k_cvtall(
    const void* s0, const void* s1, const void* s2, const void* s3,
    const void* s4, const void* s5, const void* s6, const void* s7,
    const void* s8, const void* s9, const void* s10, const void* s11,
    const void* s12, const void* s13, const void* s14, const void* s15,
    float* __restrict__ out, const int* __restrict__ flag) {
  const void* ps[16] = {s0,s1,s2,s3,s4,s5,s6,s7,s8,s9,s10,s11,s12,s13,s14,s15};
  const int offs[17] = {0,432,440,7352,14264,14296,14512,14513,30897,31025,
                        96561,162097,162609,170801,170865,170868,170869};
  int i = blockIdx.x * 256 + threadIdx.x;
  if (i >= WTOT) return;
  int s = 0;
  #pragma unroll
  for (int k = 1; k < 16; ++k) if (i >= offs[k]) s = k;
  int j = i - offs[s];
  if (*flag) out[i] = b2f(((const u16*)ps[s])[j]);
  else       out[i] = ((const float*)ps[s])[j];
}

// Wf[tap][hi][co][j] : u16 idx = tap*512 + hi*256 + co*8 + j
__global__ __launch_bounds__(256) void k_mkwf(const void* __restrict__ Wx, const void* __restrict__ Wh,
                                              const int* __restrict__ flag, u16* __restrict__ Wf) {
  int i = blockIdx.x * 256 + threadIdx.x;   // 13824
  if (i >= 13824) return;
  int j = i & 7, co = (i >> 3) & 31, hi = (i >> 8) & 1, tap = i >> 9;
  int src = tap * 256 + j * 32 + co;
  const void* P = hi ? Wh : Wx;
  u16 val;
  if (*flag) val = ((const u16*)P)[src];
  else       val = f2b(((const float*)P)[src]);
  Wf[i] = val;
}

__global__ __launch_bounds__(256) void k_counts(const int* __restrict__ kbin,
                                                float* __restrict__ cnts) {
  __shared__ float s[NCC];
  int t = threadIdx.x;
  if (t < NCC) s[t] = 0.f;
  __syncthreads();
  int i = blockIdx.x * 256 + t;
  atomicAdd(&s[kbin[i]], 1.f);
  __syncthreads();
  if (t < NCC) atomicAdd(&cnts[t], s[t]);
}

// ================= FFT kernels =================
__global__ __launch_bounds__(256) void k_fft_zy_adam(
    const float* __restrict__ pos, const void* __restrict__ yraw, size_t yoff,
    float* __restrict__ m, float* __restrict__ v, float* __restrict__ dpw,
    float2* __restrict__ cout, float ib1, float ib2, int first,
    const int* __restrict__ flag) {
  __shared__ float2 P[64*66];
  __shared__ float2 tw[64];
  int t = threadIdx.x;
  if (t < 64) { float s, c; __sincosf(-(PI2/64.f)*(float)t, &s, &c); tw[t] = make_float2(c, s); }
  size_t pb = (size_t)blockIdx.x * 4096;
  int bf = *flag;
  #pragma unroll
  for (int i = 0; i < 4; ++i) {
    int i4 = t + 256*i;
    float4 p4 = ((const float4*)(pos + pb))[i4];
    float yv[4];
    if (bf) {
      uint2 yu = ((const uint2*)((const u16*)yraw + yoff + pb))[i4];
      const u16* yp = (const u16*)&yu;
      yv[0]=b2f(yp[0]); yv[1]=b2f(yp[1]); yv[2]=b2f(yp[2]); yv[3]=b2f(yp[3]);
    } else {
      float4 y4 = ((const float4*)((const float*)yraw + yoff + pb))[i4];
      yv[0]=y4.x; yv[1]=y4.y; yv[2]=y4.z; yv[3]=y4.w;
    }
    float pv[4] = {p4.x, p4.y, p4.z, p4.w};
    float mo[4], vo[4], dd[4];
    if (!first) {
      float4 m4 = ((const float4*)(m + pb))[i4];
      float4 v4 = ((const float4*)(v + pb))[i4];
      mo[0]=m4.x; mo[1]=m4.y; mo[2]=m4.z; mo[3]=m4.w;
      vo[0]=v4.x; vo[1]=v4.y; vo[2]=v4.z; vo[3]=v4.w;
    }
    #pragma unroll
    for (int c = 0; c < 4; ++c) {
      float g = pv[c] - yv[c];
      float mi = first ? 0.1f*g : 0.9f*mo[c] + 0.1f*g;
      float vi = first ? 0.001f*g*g : 0.999f*vo[c] + 0.001f*g*g;
      mo[c] = mi; vo[c] = vi;
      dd[c] = -0.1f * (mi * ib1) / (sqrtf(vi * ib2) + 1e-7f);
    }
    ((float4*)(m + pb))[i4]   = make_float4(mo[0], mo[1], mo[2], mo[3]);
    ((float4*)(v + pb))[i4]   = make_float4(vo[0], vo[1], vo[2], vo[3]);
    ((float4*)(dpw + pb))[i4] = make_float4(dd[0], dd[1], dd[2], dd[3]);
    int base = i4 * 4;
    float2* row = P + (base >> 6)*66 + (base & 63);
    row[0] = make_float2(pv[0], 0.f);
    row[1] = make_float2(pv[1], 0.f);
    row[2] = make_float2(pv[2], 0.f);
    row[3] = make_float2(pv[3], 0.f);
  }
  __syncthreads();
  dft64<false>(P, tw, 66, 1);
  dft64<false>(P, tw, 1, 66);
  float4* dst = (float4*)(cout + pb);
  #pragma unroll
  for (int i = 0; i < 8; ++i) {
    int idx2 = (t + 256*i) * 2;
    float2 a = P[(idx2 >> 6)*66 + (idx2 & 63)];
    float2 b = P[(idx2 >> 6)*66 + (idx2 & 63) + 1];
    dst[t + 256*i] = make_float4(a.x, a.y, b.x, b.y);
  }
}

__global__ __launch_bounds__(256) void k_fft_zy(const float* __restrict__ rin,
                                                float2* __restrict__ cout) {
  __shared__ float2 P[64*66];
  __shared__ float2 tw[64];
  int t = threadIdx.x;
  if (t < 64) { float s, c; __sincosf(-(PI2/64.f)*(float)t, &s, &c); tw[t] = make_float2(c, s); }
  const float* src = rin + (size_t)blockIdx.x * 4096;
  #pragma unroll
  for (int i = 0; i < 4; ++i) {
    float4 v = ((const float4*)src)[t + 256*i];
    int base = (t + 256*i) * 4;
    float2* row = P + (base >> 6)*66 + (base & 63);
    row[0] = make_float2(v.x, 0.f);
    row[1] = make_float2(v.y, 0.f);
    row[2] = make_float2(v.z, 0.f);
    row[3] = make_float2(v.w, 0.f);
  }
  __syncthreads();
  dft64<false>(P, tw, 66, 1);
  dft64<false>(P, tw, 1, 66);
  float4* dst = (float4*)(cout + (size_t)blockIdx.x * 4096);
  #pragma unroll
  for (int i = 0; i < 8; ++i) {
    int idx2 = (t + 256*i) * 2;
    float2 a = P[(idx2 >> 6)*66 + (idx2 & 63)];
    float2 b = P[(idx2 >> 6)*66 + (idx2 & 63) + 1];
    dst[t + 256*i] = make_float4(a.x, a.y, b.x, b.y);
  }
}

__global__ __launch_bounds__(256) void k_fft_x_pow(const float2* __restrict__ cin,
                                                   const int* __restrict__ kb,
                                                   float* __restrict__ psum) {
  __shared__ float2 P[64*66];
  __shared__ float2 tw[64];
  __shared__ float pb[64];
  int t = threadIdx.x;
  if (t < 64) { float s, c; __sincosf(-(PI2/64.f)*(float)t, &s, &c); tw[t] = make_float2(c, s); pb[t] = 0.f; }
  int b = blockIdx.x >> 6, y = blockIdx.x & 63;
  #pragma unroll
  for (int i = 0; i < 8; ++i) {
    int idx2 = (t + 256*i) * 2;
    int x = idx2 >> 6, z = idx2 & 63;
    float4 v = *(const float4*)(cin + (((size_t)(b*64 + x)*64 + y)*64 + z));
    P[x*66 + z]     = make_float2(v.x, v.y);
    P[x*66 + z + 1] = make_float2(v.z, v.w);
  }
  __syncthreads();
  dft64<false>(P, tw, 1, 66);
  const float INV2 = 1.0f / ((float)VOL * (float)VOL);
  #pragma unroll
  for (int i = 0; i < 16; ++i) {
    int idx = t + 256*i;
    int x = idx >> 6, z = idx & 63;
    float2 a = P[x*66 + z];
    float pm = (a.x*a.x + a.y*a.y) * INV2;
    atomicAdd(&pb[kb[(x*64 + y)*64 + z]], pm);
  }
  __syncthreads();
  if (t < 64) atomicAdd(&psum[b*64 + t], pb[t]);
}

__global__ __launch_bounds__(256) void k_fft_x_filt(float2* __restrict__ cb,
                                                    const int* __restrict__ kb,
                                                    const float* __restrict__ psn) {
  __shared__ float2 P[64*66];
  __shared__ float2 tw[64];
  int t = threadIdx.x;
  if (t < 64) { float s, c; __sincosf(-(PI2/64.f)*(float)t, &s, &c); tw[t] = make_float2(c, s); }
  int b = blockIdx.x >> 6, y = blockIdx.x & 63;
  #pragma unroll
  for (int i = 0; i < 8; ++i) {
    int idx2 = (t + 256*i) * 2;
    int x = idx2 >> 6, z = idx2 & 63;
    float4 v = *(const float4*)(cb + (((size_t)(b*64 + x)*64 + y)*64 + z));
    P[x*66 + z]     = make_float2(v.x, v.y);
    P[x*66 + z + 1] = make_float2(v.z, v.w);
  }
  __syncthreads();
  dft64<false>(P, tw, 1, 66);
  #pragma unroll
  for (int i = 0; i < 16; ++i) {
    int idx = t + 256*i;
    int x = idx >> 6, z = idx & 63;
    float fac = sqrtf(psn[b*64 + kb[(x*64 + y)*64 + z]]);
    float2 a = P[x*66 + z];
    P[x*66 + z] = make_float2(a.x * fac, a.y * fac);
  }
  __syncthreads();
  dft64<true>(P, tw, 1, 66);
  #pragma unroll
  for (int i = 0; i < 8; ++i) {
    int idx2 = (t + 256*i) * 2;
    int x = idx2 >> 6, z = idx2 & 63;
    float2 a = P[x*66 + z], c = P[x*66 + z + 1];
    *(float4*)(cb + (((size_t)(b*64 + x)*64 + y)*64 + z)) = make_float4(a.x, a.y, c.x, c.y);
  }
}

__global__ __launch_bounds__(256) void k_fft_zy_inv(const float2* __restrict__ cin,
                                                    float* __restrict__ pos,
                                                    const void* __restrict__ xtraw, size_t xoff,
                                                    float* __restrict__ lsum,
                                                    const int* __restrict__ flag) {
  __shared__ float2 P[64*66];
  __shared__ float2 tw[64];
  __shared__ float red[256];
  int t = threadIdx.x;
  if (t < 64) { float s, c; __sincosf(-(PI2/64.f)*(float)t, &s, &c); tw[t] = make_float2(c, s); }
  size_t pb = (size_t)blockIdx.x * 4096;
  const float4* src = (const float4*)(cin + pb);
  #pragma unroll
  for (int i = 0; i < 8; ++i) {
    float4 v = src[t + 256*i];
    int idx2 = (t + 256*i) * 2;
    P[(idx2 >> 6)*66 + (idx2 & 63)]     = make_float2(v.x, v.y);
    P[(idx2 >> 6)*66 + (idx2 & 63) + 1] = make_float2(v.z, v.w);
  }
  __syncthreads();
  dft64<true>(P, tw, 1, 66);
  dft64<true>(P, tw, 66, 1);
  float* pdst = pos + pb;
  int bf = *flag;
  float lacc = 0.f;
  #pragma unroll
  for (int i = 0; i < 16; ++i) {
    int idx = t + 256*i;
    float np = pdst[idx] + P[(idx >> 6)*66 + (idx & 63)].x * (1.0f/(float)VOL);
    pdst[idx] = np;
    float xt = bf ? b2f(((const u16*)xtraw)[xoff + pb + idx])
                  : ((const float*)xtraw)[xoff + pb + idx];
    float d = xt - np;
    lacc = fmaf(d, d, lacc);
  }
  red[t] = lacc; __syncthreads();
  for (int s = 128; s > 0; s >>= 1) { if (t < s) red[t] += red[t+s]; __syncthreads(); }
  if (t == 0) atomicAdd(lsum, red[0]);
}

// ================= conv path (xyz-halo 66^3 layout) =================
__global__ __launch_bounds__(256) void k_cellin(const float* __restrict__ pos,
                                                const float* __restrict__ delta,
                                                const float* __restrict__ Win,
                                                const float* __restrict__ binf,
                                                u16* __restrict__ ci) {
  int id = blockIdx.x * 256 + threadIdx.x;
  int z = id & 63, yy = (id >> 6) & 63, x = (id >> 12) & 63, b = id >> 18;
  float acc[8];
  #pragma unroll
  for (int c = 0; c < 8; ++c) acc[c] = binf[c];
  #pragma unroll 1
  for (int tap = 0; tap < 27; ++tap) {
    int kd = tap / 9, kh = (tap / 3) % 3, kw = tap % 3;
    int nx = x + kd - 1, ny = yy + kh - 1, nz = z + kw - 1;
    if ((unsigned)nx >= 64u || (unsigned)ny >= 64u || (unsigned)nz >= 64u) continue;
    size_t n = (((size_t)b * 64 + nx) * 64 + ny) * 64 + nz;
    float p = pos[n], d = delta[n];
    const float* w = Win + tap * 16;
    #pragma unroll
    for (int c = 0; c < 8; ++c) acc[c] = fmaf(p, w[c], fmaf(d, w[8 + c], acc[c]));
  }
  u16 hh[8];
  #pragma unroll
  for (int c = 0; c < 8; ++c) hh[c] = f2b(acc[c]);
  size_t slot = (size_t)b * HS + (size_t)(x + 1) * SX + (yy + 1) * 66 + z + 1;
  *(uint4*)(ci + slot * 8) = *(uint4*)hh;
}

// MFMA ConvLSTM: W as A / act as B, xyz-halo -> 27 unconditional taps
__global__ __launch_bounds__(512, 8) void k_clstm(const u16* __restrict__ ci,
                                                  const u16* __restrict__ hC,
                                                  u16* __restrict__ hN,
                                                  u16* __restrict__ c3u,
                                                  const u16* __restrict__ Wf,
                                                  const float* __restrict__ b3f) {
  __shared__ u16 wfl[13824];          // 27648 B (only LDS)
  int t = threadIdx.x;
  for (int i = t; i < 1728; i += 512) ((uint4*)wfl)[i] = ((const uint4*)Wf)[i];
  int wv = t >> 6, l = t & 63, ln = l & 31, hi = l >> 5;
  int bid = blockIdx.x;
  int x = bid & 63, yq = (bid >> 6) & 15, b = bid >> 10;
  int y = yq * 4 + (wv >> 1), z0 = (wv & 1) * 32;
  size_t cslot = (size_t)b * HS + (size_t)(x + 1) * SX + (y + 1) * 66 + z0 + ln + 1;
  const u16* abase = (hi ? hC : ci) + cslot * 8;
  const u16* axm = abase - SX * 8;
  const u16* axp = abase + SX * 8;
  const u16* wbase = wfl + hi * 256 + ln * 8;
  __syncthreads();
  f32x16 acc;
  #pragma unroll
  for (int r = 0; r < 16; ++r) acc[r] = 0.f;
  #pragma unroll
  for (int tap = 0; tap < 27; ++tap) {
    const int dx = tap / 9, dy = (tap / 3) % 3 - 1, dz = tap % 3 - 1;
    const u16* ab = (dx == 0) ? axm : ((dx == 1) ? abase : axp);
    bf16x8 wfr = __builtin_bit_cast(bf16x8, *(const uint4*)(wbase + tap * 512));
    bf16x8 afr = __builtin_bit_cast(bf16x8, *(const uint4*)(ab + (dy * 66 + dz) * 8));
    acc = __builtin_amdgcn_mfma_f32_32x32x16_bf16(wfr, afr, acc, 0, 0, 0);
  }
  // D[co][voxel]: lane (ln,hi) holds voxel=ln, co = (r&3) + 8*(r>>2) + 4*hi
  float4 bi  = *(const float4*)(b3f + 4 * hi);
  float4 bff = *(const float4*)(b3f + 8 + 4 * hi);
  float4 bg  = *(const float4*)(b3f + 16 + 4 * hi);
  float4 bo_ = *(const float4*)(b3f + 24 + 4 * hi);
  const float* bip = (const float*)&bi;
  const float* bfp = (const float*)&bff;
  const float* bgp = (const float*)&bg;
  const float* bop = (const float*)&bo_;
  uint2 cu = *(const uint2*)(c3u + cslot * 8 + hi * 4);
  const u16* cp = (const u16*)&cu;
  u16 cw[4], hw[4];
  #pragma unroll
  for (int q = 0; q < 4; ++q) {
    float zi  = acc[q]      + bip[q];
    float zf  = acc[4 + q]  + bfp[q];
    float zg  = acc[8 + q]  + bgp[q];
    float zo_ = acc[12 + q] + bop[q];
    float cn = fsig(zf) * b2f(cp[q]) + fsig(zi) * ftanh(zg);
    cw[q] = f2b(cn);
    hw[q] = f2b(fsig(zo_) * ftanh(cn));
  }
  *(uint2*)(c3u + cslot * 8 + hi * 4) = *(uint2*)cw;
  *(uint2*)(hN + cslot * 8 + hi * 4)  = *(uint2*)hw;
}

__global__ __launch_bounds__(256) void k_wout(const u16* __restrict__ h,
                                              const float* __restrict__ Wo,
                                              const float* __restrict__ bo,
                                              float* __restrict__ dpw) {
  int id = blockIdx.x * 256 + threadIdx.x;
  int z = id & 63, yy = (id >> 6) & 63, x = (id >> 12) & 63, b = id >> 18;
  size_t cslot = (size_t)b * HS + (size_t)(x + 1) * SX + (yy + 1) * 66 + z + 1;
  const u16* hb = h + cslot * 8;
  const u16* hxm = hb - SX * 8;
  const u16* hxp = hb + SX * 8;
  float acc = bo[0];
  #pragma unroll 1
  for (int tap = 0; tap < 27; ++tap) {
    int kd = tap / 9, kh = (tap / 3) % 3, kw = tap % 3;
    const u16* ab = (kd == 0) ? hxm : ((kd == 1) ? hb : hxp);
    uint4 a = *(const uint4*)(ab + ((kh - 1) * 66 + (kw - 1)) * 8);
    const u16* hp = (const u16*)&a;
    const float* w = Wo + tap * 8;
    #pragma unroll
    for (int c = 0; c < 8; ++c) acc = fmaf(b2f(hp[c]), w[c], acc);
  }
  dpw[id] = acc;
}

// ================= small dense LSTM branch =================
__global__ __launch_bounds__(256) void k_small(const float* __restrict__ psp,
                                               const float* __restrict__ psd,
                                               const float* __restrict__ cnts,
                                               const float* __restrict__ Wd1,
                                               const float* __restrict__ bd1,
                                               const float* __restrict__ Wlx,
                                               const float* __restrict__ Wlh,
                                               const float* __restrict__ bl,
                                               const float* __restrict__ Wd2,
                                               const float* __restrict__ bd2,
                                               const float* __restrict__ Wc1,
                                               const float* __restrict__ bc1,
                                               float* __restrict__ h1, float* __restrict__ c1,
                                               float* __restrict__ psn) {
  __shared__ float lp[128], x1[128], hs[128], zz[512], lps[66];
  int t = threadIdx.x, b = blockIdx.x;
  if (t < 64) {
    lp[t]      = __log10f(fmaxf(psp[b*64 + t] / cnts[t] * 8.0e6f, 1e-30f));
    lp[64 + t] = __log10f(fmaxf(psd[b*64 + t] / cnts[t] * 8.0e6f, 1e-30f));
  }
  if (t < 128) hs[t] = h1[b*128 + t];
  __syncthreads();
  if (t < 128) {
    float a = bd1[t];
    for (int j = 0; j < 128; ++j) a = fmaf(lp[j], Wd1[j*128 + t], a);
    x1[t] = a;
  }
  __syncthreads();
  for (int k = t; k < 512; k += 256) {
    float a = bl[k];
    for (int u = 0; u < 128; ++u)
      a = fmaf(x1[u], Wlx[u*512 + k], fmaf(hs[u], Wlh[u*512 + k], a));
    zz[k] = a;
  }
  __syncthreads();
  if (t < 128) {
    float cv = fsig(zz[128 + t]) * c1[b*128 + t] + fsig(zz[t]) * ftanh(zz[256 + t]);
    c1[b*128 + t] = cv;
    float hv = fsig(zz[384 + t]) * ftanh(cv);
    h1[b*128 + t] = hv; hs[t] = hv;
  }
  __syncthreads();
  if (t < 64) {
    float a = bd2[t];
    for (int u = 0; u < 128; ++u) a = fmaf(hs[u], Wd2[u*64 + t], a);
    lps[t + 1] = a;
  }
  __syncthreads();
  if (t < 64) {
    float a = fmaf(Wc1[1], lps[t + 1], bc1[0]);
    if (t > 0)  a = fmaf(Wc1[0], lps[t], a);
    if (t < 63) a = fmaf(Wc1[2], lps[t + 2], a);
    psn[b*64 + t] = __expf(a);
  }
}

// ================= output =================
__global__ __launch_bounds__(256) void k_out(const float* __restrict__ pos, void* __restrict__ outp,
                                             size_t eoff, const int* __restrict__ flag) {
  size_t i = (size_t)blockIdx.x * 256 + threadIdx.x;
  if (*flag) ((u16*)outp)[eoff + i] = f2b(pos[i]);
  else       ((float*)outp)[eoff + i] = pos[i];
}

__global__ void k_loss(const float* __restrict__ lsum, void* __restrict__ outp,
                       const int* __restrict__ flag) {
  float l = lsum[0] * (1.0f / (float)TOT);
  if (*flag) ((u16*)outp)[TOT] = f2b(l);
  else       ((float*)outp)[TOT] = l;
}

__global__ void k_sent(u16* __restrict__ outp) { outp[0] = f2b(1000.0f); }

extern "C" void kernel_launch(void* const* d_in, const int* in_sizes, int n_in,
                              void* d_out, int out_size, void* d_ws, size_t ws_size,
                              hipStream_t stream) {
  const void* x_init = d_in[0];
  const void* y      = d_in[1];
  const void* x_true = d_in[2];
  const int*  kbin   = (const int*)d_in[3];

  int nbs = 0;
  for (int cand = 8; cand >= 1; cand >>= 1) {
    size_t n1c = (size_t)cand * VOL;
    size_t slc = (size_t)cand * HS;
    size_t need = 4 * n1c * 4            // pos,m,v,dpw f32
                + 4 * slc * 16           // c3u,ci,hA,hB (8 u16 per slot)
                + n1c * 8                // cb float2
                + (171008 + 6912 + (size_t)cand * (192 + 256) + 96) * 4;
    if (need <= ws_size) { nbs = cand; break; }
  }
  if (nbs == 0) { k_sent<<<1, 1, 0, stream>>>((u16*)d_out); return; }

  size_t n1 = (size_t)nbs * VOL;
  size_t sl = (size_t)nbs * HS;
  float* ws   = (float*)d_ws;
  float* pos  = ws;
  float* m    = pos + n1;
  float* v    = m + n1;
  float* dpw  = v + n1;
  u16*  c3u   = (u16*)(dpw + n1);     // sl*8 u16 each
  u16*  ci    = c3u + sl*8;
  u16*  hA    = ci + sl*8;
  u16*  hB    = hA + sl*8;
  float2* cb  = (float2*)(hB + sl*8); // n1 float2 (separate, no alias)
  float* wbuf = (float*)((float*)cb + n1*2);  // 171008 f32
  u16*  Wf    = (u16*)(wbuf + 171008);        // 13824 u16
  float* psp  = wbuf + 171008 + 6912;
  float* psd  = psp + (size_t)nbs*64;
  float* psn  = psd + (size_t)nbs*64;
  float* cnts = psn + (size_t)nbs*64;
  float* lsum = cnts + 64;            // 8
  float* h1   = lsum + 8;
  float* c1   = h1 + (size_t)nbs*128;
  int*   flag = (int*)(c1 + (size_t)nbs*128);

  float* Win_f = wbuf + 0;     float* bin_f = wbuf + 432;
  float* b3_f  = wbuf + 14264; float* Wo_f  = wbuf + 14296;
  float* bo_f  = wbuf + 14512; float* Wd1_f = wbuf + 14513;
  float* bd1_f = wbuf + 30897; float* Wlx_f = wbuf + 31025;
  float* Wlh_f = wbuf + 96561; float* bl_f  = wbuf + 162097;
  float* Wd2_f = wbuf + 162609; float* bd2_f = wbuf + 170801;
  float* Wc1_f = wbuf + 170865; float* bc1_f = wbuf + 170868;

  const int CB = (int)(n1 / 256);

  k_sniff<<<1, 256, 0, stream>>>((const u16*)x_init, flag);
  k_cvtall<<<(WTOT + 255) / 256, 256, 0, stream>>>(
      d_in[4], d_in[5], d_in[6], d_in[7], d_in[8], d_in[9], d_in[10], d_in[11],
      d_in[12], d_in[13], d_in[14], d_in[15], d_in[16], d_in[17], d_in[18], d_in[19],
      wbuf, flag);
  k_mkwf<<<54, 256, 0, stream>>>(d_in[6], d_in[7], flag, Wf);
  hipMemsetAsync(cnts, 0, 72 * 4, stream);      // cnts + lsum
  k_counts<<<VOL / 256, 256, 0, stream>>>(kbin, cnts);

  for (int b0 = 0; b0 < NB; b0 += nbs) {
    hipMemsetAsync(c3u, 0, sl * 64, stream);    // c3u,ci,hA,hB contiguous (halos stay 0)
    hipMemsetAsync(h1, 0, (size_t)nbs * 256 * 4, stream);
    k_cvt<<<CB, 256, 0, stream>>>(x_init, (size_t)b0 * VOL, pos, flag);

    u16* hC = hA;
    u16* hN = hB;
    for (int t = 1; t <= 4; ++t) {
      float ib1 = (float)(1.0 / (1.0 - pow(0.9, (double)t)));
      float ib2 = (float)(1.0 / (1.0 - pow(0.999, (double)t)));

      hipMemsetAsync(psp, 0, (size_t)nbs * 128 * 4, stream);   // psp + psd
      k_fft_zy_adam<<<nbs * 64, 256, 0, stream>>>(pos, y, (size_t)b0 * VOL, m, v, dpw,
                                                  cb, ib1, ib2, t == 1, flag);
      k_fft_x_pow<<<nbs * 64, 256, 0, stream>>>(cb, kbin, psp);
      k_fft_zy<<<nbs * 64, 256, 0, stream>>>(dpw, cb);
      k_fft_x_pow<<<nbs * 64, 256, 0, stream>>>(cb, kbin, psd);

      k_cellin<<<CB, 256, 0, stream>>>(pos, dpw, Win_f, bin_f, ci);
      k_clstm<<<nbs * 1024, 512, 0, stream>>>(ci, hC, hN, c3u, Wf, b3_f);
      k_wout<<<CB, 256, 0, stream>>>(hN, Wo_f, bo_f, dpw);

      k_small<<<nbs, 256, 0, stream>>>(psp, psd, cnts, Wd1_f, bd1_f, Wlx_f, Wlh_f, bl_f,
                                       Wd2_f, bd2_f, Wc1_f, bc1_f, h1, c1, psn);

      k_fft_zy<<<nbs * 64, 256, 0, stream>>>(dpw, cb);
      k_fft_x_filt<<<nbs * 64, 256, 0, stream>>>(cb, kbin, psn);
      k_fft_zy_inv<<<nbs * 64, 256, 0, stream>>>(cb, pos, x_true, (size_t)b0 * VOL, lsum, flag);

      u16* tmp = hC; hC = hN; hN = tmp;
    }
    k_out<<<CB, 256, 0, stream>>>(pos, d_out, (size_t)b0 * VOL, flag);
  }
  k_loss<<<1, 1, 0, stream>>>(lsum, d_out, flag);
}